// Round 15
// baseline (662.361 us; speedup 1.0000x reference)
//
#include <hip/hip_runtime.h>
#include <hip/hip_fp16.h>

#define DIM 768
#define HID 24576
#define DENSE 3072
#define LL 24
#define MROWS 1536
#define KSEL 16
#define NC 24              // certified candidate rank (true top-16 in approx top-24)
#define CAP 40             // candidate capacity (NC + threshold ties)
#define MF_TOT 96          // MROWS/16
#define ENC2_NT 96         // DENSE/32 K-tiles for enc2 (BK=32)
#define DELTA 2e-3f        // band half-width >= 2x max |fp16-z - true z| (~5e-4)

typedef _Float16 f16;
typedef __attribute__((ext_vector_type(8))) _Float16 f16x8;
typedef __attribute__((ext_vector_type(4))) float f32x4;
typedef const __attribute__((address_space(1))) char* gcp;
typedef __attribute__((address_space(3))) char* lcp;

__device__ __forceinline__ float gelu_exact(float x) {
    return 0.5f * x * (1.0f + erff(x * 0.7071067811865476f));
}

// ---------------------------------------------------------- fp16 hi/lo split
__device__ __forceinline__ void split8(const float4& v0, const float4& v1,
                                       f16x8& hi, f16x8& lo) {
    float vv[8] = {v0.x, v0.y, v0.z, v0.w, v1.x, v1.y, v1.z, v1.w};
#pragma unroll
    for (int j = 0; j < 8; ++j) {
        f16 h = (f16)vv[j];
        hi[j] = h;
        lo[j] = (f16)((vv[j] - (float)h) * 2048.0f);
    }
}

// Fragment packing: chunk = 64 lanes x 16B; lane holds 8 halves for
// (row = base + (lane&15), k = ks*32 + (lane>>4)*8 + j). Same packing for A
// and W => K-slot permutation cancels inside MFMA.

// ---- hi+lo packs (3-term GEMM operands) ----
template <int KTOT, int RFTOT>
__global__ __launch_bounds__(256) void apack_kernel(
    const float* __restrict__ src, f16* __restrict__ dst) {
    int c = blockIdx.x * 4 + (threadIdx.x >> 6);
    int lane = threadIdx.x & 63;
    int rf = c % RFTOT, ks = c / RFTOT;
    int m = rf * 16 + (lane & 15);
    int k = ks * 32 + (lane >> 4) * 8;
    const float4* s = (const float4*)(src + (size_t)m * (KTOT * 32) + k);
    f16x8 hi, lo;
    split8(s[0], s[1], hi, lo);
    char* base = (char*)dst + (size_t)c * 2048 + lane * 16;
    *(f16x8*)base = hi;
    *(f16x8*)(base + 1024) = lo;
}

__global__ __launch_bounds__(256) void xcpack_kernel(
    const float* __restrict__ x, const float* __restrict__ b2,
    f16* __restrict__ dst) {
    int c = blockIdx.x * 4 + (threadIdx.x >> 6);
    int lane = threadIdx.x & 63;
    int rf = c % MF_TOT, ks = c / MF_TOT;
    int m = rf * 16 + (lane & 15);
    int k = ks * 32 + (lane >> 4) * 8;
    const float4* sx = (const float4*)(x + (size_t)m * DIM + k);
    const float4* sb = (const float4*)(b2 + (m % LL) * DIM + k);
    float4 v0 = sx[0], v1 = sx[1], b0 = sb[0], b1 = sb[1];
    v0.x -= b0.x; v0.y -= b0.y; v0.z -= b0.z; v0.w -= b0.w;
    v1.x -= b1.x; v1.y -= b1.y; v1.z -= b1.z; v1.w -= b1.w;
    f16x8 hi, lo;
    split8(v0, v1, hi, lo);
    char* base = (char*)dst + (size_t)c * 2048 + lane * 16;
    *(f16x8*)base = hi;
    *(f16x8*)(base + 1024) = lo;
}

template <int KTOT>
__global__ __launch_bounds__(256) void wpack_kernel(
    const float* __restrict__ src, f16* __restrict__ dst, int row0) {
    int c = blockIdx.x * 4 + (threadIdx.x >> 6);
    int lane = threadIdx.x & 63;
    int nf = c & 7; int t = c >> 3; int ks = t % KTOT; int nb = t / KTOT;
    int n = row0 + nb * 128 + nf * 16 + (lane & 15);
    int k = ks * 32 + (lane >> 4) * 8;
    const float4* s = (const float4*)(src + (size_t)n * (KTOT * 32) + k);
    f16x8 hi, lo;
    split8(s[0], s[1], hi, lo);
    char* base = (char*)dst + (size_t)c * 2048 + lane * 16;
    *(f16x8*)base = hi;
    *(f16x8*)(base + 1024) = lo;
}

// ---- hi-only packs (enc2 approx path) ----
__global__ __launch_bounds__(256) void apackhi_kernel(
    const float* __restrict__ src, f16* __restrict__ dst) {
    int c = blockIdx.x * 4 + (threadIdx.x >> 6);
    int lane = threadIdx.x & 63;
    int rf = c % MF_TOT, ks = c / MF_TOT;
    int m = rf * 16 + (lane & 15);
    int k = ks * 32 + (lane >> 4) * 8;
    const float4* s = (const float4*)(src + (size_t)m * DENSE + k);
    float4 v0 = s[0], v1 = s[1];
    float vv[8] = {v0.x, v0.y, v0.z, v0.w, v1.x, v1.y, v1.z, v1.w};
    f16x8 hi;
#pragma unroll
    for (int j = 0; j < 8; ++j) hi[j] = (f16)vv[j];
    *(f16x8*)((char*)dst + (size_t)c * 1024 + lane * 16) = hi;
}

__global__ __launch_bounds__(256) void wpackhi_kernel(
    const float* __restrict__ src, f16* __restrict__ dst) {
    int c = blockIdx.x * 4 + (threadIdx.x >> 6);
    int lane = threadIdx.x & 63;
    int nf = c & 7; int t = c >> 3; int ks = t % 96; int nb = t / 96;
    int n = nb * 128 + nf * 16 + (lane & 15);
    int k = ks * 32 + (lane >> 4) * 8;
    const float4* s = (const float4*)(src + (size_t)n * DENSE + k);
    float4 v0 = s[0], v1 = s[1];
    float vv[8] = {v0.x, v0.y, v0.z, v0.w, v1.x, v1.y, v1.z, v1.w};
    f16x8 hi;
#pragma unroll
    for (int j = 0; j < 8; ++j) hi[j] = (f16)vv[j];
    *(f16x8*)((char*)dst + (size_t)c * 1024 + lane * 16) = hi;
}

// --------------------------------------------- transpose decoder_w1 -> fp16
// src [DENSE][HID] fp32  ->  dst [HID][DENSE] fp16
__global__ __launch_bounds__(256) void transpose_w1_kernel(
    const float* __restrict__ src, __half* __restrict__ dst) {
    __shared__ float tile[32][33];
    const int c0 = blockIdx.x * 32;   // along HID
    const int r0 = blockIdx.y * 32;   // along DENSE
    const int tx = threadIdx.x & 31, ty = threadIdx.x >> 5;
#pragma unroll
    for (int i = 0; i < 32; i += 8)
        tile[ty + i][tx] = src[(size_t)(r0 + ty + i) * HID + c0 + tx];
    __syncthreads();
#pragma unroll
    for (int i = 0; i < 32; i += 8)
        dst[(size_t)(c0 + ty + i) * DENSE + r0 + tx] = __float2half(tile[tx][ty + i]);
}

// ------------------------------------------------- split-fp16 MFMA GEMM (NT)
// 3-term fp32-equivalent (enc1 EPI=1, dec2 EPI=2) — proven m97-style structure
template <int KTOT, int EPI>
__global__ __launch_bounds__(256, 2) void mfma_nt_kernel(
    const f16* __restrict__ Apk, const f16* __restrict__ Wpk,
    const float* __restrict__ bias, float* __restrict__ C,
    int N, int n0g) {
    __shared__ __align__(16) char lds[2][32768];
    const int tid = threadIdx.x;
    const int lane = tid & 63, wave = tid >> 6;
    const int mb = blockIdx.x, nb = blockIdx.y;
    const int wr = wave >> 1, wc = wave & 1;
    const char* ApkB = (const char*)Apk;
    const char* WpkB = (const char*)Wpk;

    f32x4 accH[4][4] = {}; f32x4 accL[4][4] = {};

    auto stage = [&](int buf, int ks) {
        const char* Ar = ApkB + (size_t)(ks * MF_TOT + mb * 8) * 2048;
        const char* Wr = WpkB + (size_t)(nb * KTOT + ks) * 16384;
#pragma unroll
        for (int q = 0; q < 8; ++q) {
            int c = wave * 8 + q;
            const char* src = (c < 16 ? Ar + c * 1024 : Wr + (c - 16) * 1024) + lane * 16;
            char* dst = &lds[buf][c * 1024];
            __builtin_amdgcn_global_load_lds((gcp)src, (lcp)dst, 16, 0, 0);
        }
    };

    stage(0, 0);
    for (int ks = 0; ks < KTOT; ++ks) {
        int cur = ks & 1;
        __syncthreads();
        if (ks + 1 < KTOT) stage(cur ^ 1, ks + 1);
        const char* Bf = lds[cur];
        f16x8 Ahi[4], Alo[4], Whi[4], Wlo[4];
#pragma unroll
        for (int i = 0; i < 4; ++i) {
            Ahi[i] = *(const f16x8*)(Bf + ((wr * 4 + i) * 2 + 0) * 1024 + lane * 16);
            Alo[i] = *(const f16x8*)(Bf + ((wr * 4 + i) * 2 + 1) * 1024 + lane * 16);
            Whi[i] = *(const f16x8*)(Bf + 16384 + ((wc * 4 + i) * 2 + 0) * 1024 + lane * 16);
            Wlo[i] = *(const f16x8*)(Bf + 16384 + ((wc * 4 + i) * 2 + 1) * 1024 + lane * 16);
        }
#pragma unroll
        for (int i = 0; i < 4; ++i)
#pragma unroll
            for (int j = 0; j < 4; ++j) {
                accH[i][j] = __builtin_amdgcn_mfma_f32_16x16x32_f16(Ahi[i], Whi[j], accH[i][j], 0, 0, 0);
                accL[i][j] = __builtin_amdgcn_mfma_f32_16x16x32_f16(Ahi[i], Wlo[j], accL[i][j], 0, 0, 0);
                accL[i][j] = __builtin_amdgcn_mfma_f32_16x16x32_f16(Alo[i], Whi[j], accL[i][j], 0, 0, 0);
            }
    }
    const int rbase = mb * 128 + wr * 64 + (lane >> 4) * 4;
    const int cb = n0g + nb * 128 + wc * 64 + (lane & 15);
#pragma unroll
    for (int j = 0; j < 4; ++j) {
        int col = cb + j * 16;
        float bn = (EPI == 2) ? 0.0f : bias[col];
#pragma unroll
        for (int i = 0; i < 4; ++i) {
#pragma unroll
            for (int e = 0; e < 4; ++e) {
                int row = rbase + i * 16 + e;
                float v = accH[i][j][e] + accL[i][j][e] * (1.0f / 2048.0f);
                if (EPI == 1)       v = gelu_exact(v + bn);
                else if (EPI == 0)  v += bn;
                else                v += bias[(row % LL) * N + col];
                C[(size_t)row * N + col] = v;
            }
        }
    }
}

// ---- enc2 v7: v3 skeleton, BM=128 -> 16KB/buf, 3 blocks/CU, zero grid tail
// z[m,n] ~= sum_k h[m,k]*w2[n,k] + b2[n]  (hi-term only, fp32 accum, fp16 out)
// 4 waves (2M x 2N, 64x64/wave, 16 MFMA per wave-phase), 3-buffer/1-barrier,
// counted vmcnt(4). Grid 2304 = 3 blocks/CU x 3 exact generations.
__global__ __launch_bounds__(256, 3) void enc2v7_kernel(
    const f16* __restrict__ Apk, const f16* __restrict__ Wpk,
    const float* __restrict__ b2, __half* __restrict__ z) {
    __shared__ __align__(16) char lds[3][16384];   // per buf: A 8KB | W 8KB
    const int tid = threadIdx.x;
    const int lane = tid & 63, wave = tid >> 6;    // 4 waves
    // bijective XCD-chunked swizzle: 2304 blocks = 8 x 288
    int f = blockIdx.y * 12 + blockIdx.x;
    int ff = (f & 7) * 288 + (f >> 3);
    const int mb = ff % 12, nb = ff / 12;          // BM=128 (12), BN=128 (192)
    const int wr = wave >> 1, wc = wave & 1;       // 2M x 2N wave grid
    const char* ApkB = (const char*)Apk;
    const char* WpkB = (const char*)Wpk;
    f32x4 acc[4][4] = {};

    auto stage = [&](int t) {                      // tile t -> buf t%3 (4 loads)
        if (t >= ENC2_NT) return;
        char* dst = lds[t % 3];
        const char* Asrc = ApkB + ((size_t)t * MF_TOT + mb * 8) * 1024;
#pragma unroll
        for (int q = 0; q < 2; ++q)
            __builtin_amdgcn_global_load_lds(
                (gcp)(Asrc + tid * 16 + q * 4096),
                (lcp)(dst + (tid & ~63) * 16 + q * 4096), 16, 0, 0);
        const char* Wsrc = WpkB + ((size_t)nb * 96 + t) * 8192;
#pragma unroll
        for (int q = 0; q < 2; ++q)
            __builtin_amdgcn_global_load_lds(
                (gcp)(Wsrc + tid * 16 + q * 4096),
                (lcp)(dst + 8192 + (tid & ~63) * 16 + q * 4096), 16, 0, 0);
    };

    stage(0); stage(1);
    asm volatile("s_waitcnt vmcnt(4)" ::: "memory");   // tile0 landed, tile1 in flight
    __builtin_amdgcn_s_barrier();

    for (int t = 0; t < ENC2_NT; ++t) {
        const char* Bf = lds[t % 3];
        f16x8 Af[4], Wf[4];
#pragma unroll
        for (int i = 0; i < 4; ++i) {
            Af[i] = *(const f16x8*)(Bf + (wr * 4 + i) * 1024 + lane * 16);
            Wf[i] = *(const f16x8*)(Bf + 8192 + (wc * 4 + i) * 1024 + lane * 16);
        }
        stage(t + 2);          // targets buf[(t+2)%3]: not read this phase or next
        __builtin_amdgcn_s_setprio(1);
#pragma unroll
        for (int i = 0; i < 4; ++i)
#pragma unroll
            for (int j = 0; j < 4; ++j)
                acc[i][j] = __builtin_amdgcn_mfma_f32_16x16x32_f16(Af[i], Wf[j], acc[i][j], 0, 0, 0);
        __builtin_amdgcn_s_setprio(0);
        // boundary: t+1's loads (issued phase t-1) must land; t+2's 4 may fly
        if (t < ENC2_NT - 2)      asm volatile("s_waitcnt vmcnt(4)" ::: "memory");
        else if (t < ENC2_NT - 1) asm volatile("s_waitcnt vmcnt(0)" ::: "memory");
        if (t < ENC2_NT - 1) __builtin_amdgcn_s_barrier();
    }
    // epilogue: fp16 z
    const int rbase = mb * 128 + wr * 64 + (lane >> 4) * 4;
    const int cb = nb * 128 + wc * 64 + (lane & 15);
#pragma unroll
    for (int j = 0; j < 4; ++j) {
        int col = cb + j * 16;
        float bn = b2[col];
#pragma unroll
        for (int r = 0; r < 4; ++r)
#pragma unroll
            for (int e = 0; e < 4; ++e)
                z[(size_t)(rbase + r * 16 + e) * HID + col] = __float2half(acc[r][j][e] + bn);
    }
}

// ---------------------------------------- radix-select candidates (key >= T)
// fp16 z; u16 monotone keys staged in LDS; T = NC-th largest (refined to 16 bits)
__global__ __launch_bounds__(512) void topksel_kernel(
    const __half* __restrict__ z, int* __restrict__ candi, int* __restrict__ candn) {
    __shared__ unsigned short keys[HID];   // 48 KB
    __shared__ unsigned hist[4096];        // 16 KB
    __shared__ int sc[512];
    __shared__ int sB1, sA, sT, scnt;
    const int row = blockIdx.x, tid = threadIdx.x;
    const uint4* zr = reinterpret_cast<const uint4*>(z + (size_t)row * HID);
#pragma unroll
    for (int i = 0; i < 8; ++i) hist[tid + i * 512] = 0;
    if (tid == 0) scnt = 0;
    __syncthreads();
    // pass 1: stage keys + 12-bit histogram (key[15:4])
#pragma unroll
    for (int i = 0; i < 6; ++i) {
        uint4 v = zr[tid + i * 512];
        unsigned w[4] = {v.x, v.y, v.z, v.w};
        int base = (tid + i * 512) * 8;
#pragma unroll
        for (int q = 0; q < 4; ++q)
#pragma unroll
            for (int s = 0; s < 2; ++s) {
                unsigned b = (w[q] >> (16 * s)) & 0xFFFFu;
                unsigned kk = b ^ ((b & 0x8000u) ? 0xFFFFu : 0x8000u);
                keys[base + q * 2 + s] = (unsigned short)kk;
                atomicAdd(&hist[kk >> 4], 1u);
            }
    }
    __syncthreads();
    // descending crossing scan for rank NC
    {
        int part = 0;
#pragma unroll
        for (int j = 0; j < 8; ++j) part += (int)hist[4095 - 8 * tid - j];
        sc[tid] = part;
        __syncthreads();
        for (int off = 1; off < 512; off <<= 1) {
            int v = (tid >= off) ? sc[tid - off] : 0;
            __syncthreads();
            sc[tid] += v;
            __syncthreads();
        }
        int incl = sc[tid], pre = incl - part;
        if (pre < NC && NC <= incl) {
            int cum = pre;
            for (int j = 0; j < 8; ++j) {
                int b = 4095 - 8 * tid - j;
                int hh = (int)hist[b];
                if (cum + hh >= NC) { sB1 = b; sA = cum; break; }
                cum += hh;
            }
        }
    }
    __syncthreads();
    const int B1 = sB1, t2 = NC - sA;      // t2 >= 1
    // pass 2: 4-bit sub-histogram within bin B1
    if (tid < 16) hist[tid] = 0;
    __syncthreads();
#pragma unroll
    for (int i = 0; i < 48; ++i) {
        unsigned kk = keys[tid + i * 512];
        if ((int)(kk >> 4) == B1) atomicAdd(&hist[kk & 0xF], 1u);
    }
    __syncthreads();
    if (tid == 0) {
        int cum = 0;
        for (int b = 15; b >= 0; --b) {
            cum += (int)hist[b];
            if (cum >= t2) { sT = (B1 << 4) | b; break; }
        }
    }
    __syncthreads();
    const unsigned T = (unsigned)sT;
    // pass 3: compact indices with key >= T
#pragma unroll
    for (int i = 0; i < 48; ++i) {
        int idx = tid + i * 512;
        if ((unsigned)keys[idx] >= T) {
            int p = atomicAdd(&scnt, 1);
            if (p < CAP) candi[(size_t)row * CAP + p] = idx;
        }
    }
    __syncthreads();
    if (tid == 0) candn[row] = min(scnt, CAP);
}

// ----------------- epsilon-band rescue v2: fully wave-parallel ranking
// approx values av from fp16 z (|av - true| <= ~5e-4 << DELTA/2).
// Wave 0 holds all <=40 candidates in lanes; all-pairs shfl ranking gives
// v16 and final ranks. Band members (|av-v16|<=DELTA) get exact fp32 dots.
__global__ __launch_bounds__(256) void resolve16_kernel(
    const __half* __restrict__ z, const float* __restrict__ h,
    const float* __restrict__ w2, const float* __restrict__ b2,
    const int* __restrict__ candi, const int* __restrict__ candn,
    float* __restrict__ tkv, int* __restrict__ tki) {
    const int row = blockIdx.x, tid = threadIdx.x;
    const int lane = tid & 63, wave = tid >> 6;
    __shared__ float hs[DENSE];        // 12 KB
    __shared__ float av[64];
    __shared__ int ci[64];
    __shared__ int bnd[CAP];
    __shared__ int nb_s;
    const int cnt = candn[row];
    // all threads stage h row
    const float4* hr = reinterpret_cast<const float4*>(h + (size_t)row * DENSE);
#pragma unroll
    for (int j = 0; j < 3; ++j)
        reinterpret_cast<float4*>(hs)[tid + j * 256] = hr[tid + j * 256];
    // wave 0: load candidates into lanes, rank via all-pairs shuffles
    if (wave == 0) {
        float myv = -1e30f;
        int myi = 0x7fffffff;
        if (lane < cnt) {
            myi = candi[(size_t)row * CAP + lane];
            myv = __half2float(z[(size_t)row * HID + myi]);
        }
        int rank = 0;
#pragma unroll
        for (int o = 0; o < CAP; ++o) {
            float ov = __shfl(myv, o);
            int oi = __shfl(myi, o);
            rank += ((ov > myv) || (ov == myv && oi < myi)) ? 1 : 0;
        }
        // v16 = value of the unique lane with rank 15 (cnt >= NC > 16)
        unsigned long long m15 = __ballot(rank == 15);
        int sl = (int)__builtin_ctzll(m15);
        float v16 = __shfl(myv, sl);
        bool band = (lane < cnt) && (fabsf(myv - v16) <= DELTA);
        unsigned long long bm = __ballot(band);
        if (lane == 0) nb_s = (int)__popcll(bm);
        if (band) {
            int p = (int)__popcll(bm & ((1ull << lane) - 1ull));
            bnd[p] = lane;
        }
        av[lane] = myv;
        ci[lane] = myi;
    }
    __syncthreads();
    // exact fp32 dots for band members (one wave each; nb typically ~2)
    const int nbn = nb_s;
    for (int b = wave; b < nbn; b += 4) {
        int c = bnd[b];
        int n = ci[c];
        const float4* wr = reinterpret_cast<const float4*>(w2 + (size_t)n * DENSE);
        float p = 0.0f;
#pragma unroll
        for (int j = 0; j < 12; ++j) {
            float4 a = reinterpret_cast<const float4*>(hs)[lane + j * 64];
            float4 w = wr[lane + j * 64];
            p += a.x * w.x + a.y * w.y + a.z * w.z + a.w * w.w;
        }
#pragma unroll
        for (int off = 32; off >= 1; off >>= 1) p += __shfl_down(p, off);
        if (lane == 0) av[c] = p + b2[n];   // replace approx with exact
    }
    __syncthreads();
    // wave 0: final rank over mixed values, scatter rank<16 directly
    if (wave == 0) {
        float v = av[lane];
        int idx = ci[lane];
        int rank = 0;
#pragma unroll
        for (int o = 0; o < CAP; ++o) {
            float ov = __shfl(v, o);
            int oi = __shfl(idx, o);
            rank += ((ov > v) || (ov == v && oi < idx)) ? 1 : 0;
        }
        if (lane < cnt && rank < KSEL) {
            tkv[row * KSEL + rank] = fmaxf(v, 0.0f);   // act_fn = ReLU
            tki[row * KSEL + rank] = idx;
        }
    }
}

// ------------------------------------------------------------ sparse decode
// block row: d[row,:] = gelu( sum_k val_k * w1t[idx_k, :] + b1 )  (coalesced)
__global__ __launch_bounds__(256) void sparse_decode_kernel(
    const float* __restrict__ tkv, const int* __restrict__ tki,
    const __half* __restrict__ w1t, const float* __restrict__ b1,
    float* __restrict__ D) {
    const int row = blockIdx.x, tid = threadIdx.x;
    __shared__ float sv[KSEL];
    __shared__ int si[KSEL];
    if (tid < KSEL) { sv[tid] = tkv[row * KSEL + tid]; si[tid] = tki[row * KSEL + tid]; }
    __syncthreads();
    float2 acc[6] = {};
#pragma unroll 1
    for (int k = 0; k < KSEL; ++k) {
        const float v = sv[k];
        const __half2* wr = reinterpret_cast<const __half2*>(w1t + (size_t)si[k] * DENSE);
#pragma unroll
        for (int j = 0; j < 6; ++j) {
            float2 f = __half22float2(wr[tid + j * 256]);
            acc[j].x = fmaf(v, f.x, acc[j].x);
            acc[j].y = fmaf(v, f.y, acc[j].y);
        }
    }
#pragma unroll
    for (int j = 0; j < 6; ++j) {
        int dd = (tid + j * 256) * 2;
        D[(size_t)row * DENSE + dd]     = gelu_exact(acc[j].x + b1[dd]);
        D[(size_t)row * DENSE + dd + 1] = gelu_exact(acc[j].y + b1[dd + 1]);
    }
}

// ---------------------------------------------------------------- launch
extern "C" void kernel_launch(void* const* d_in, const int* in_sizes, int n_in,
                              void* d_out, int out_size, void* d_ws, size_t ws_size,
                              hipStream_t stream) {
    const float* x      = (const float*)d_in[0];
    const float* enc_w1 = (const float*)d_in[1];
    const float* enc_b1 = (const float*)d_in[2];
    const float* enc_w2 = (const float*)d_in[3];
    const float* enc_b2 = (const float*)d_in[4];
    const float* dec_w1 = (const float*)d_in[5];
    const float* dec_b1 = (const float*)d_in[6];
    const float* dec_w2 = (const float*)d_in[7];
    const float* dec_b2 = (const float*)d_in[8];
    float* out = (float*)d_out;

    char* ws = (char*)d_ws;
    size_t off = 0;
    // region1: Wpk (enc2 W hi-only) -> later w1t (both 151.0 MB; Wpk dead after enc2)
    f16*    Wpk = (f16*)(ws + off);
    __half* w1t = (__half*)(ws + off); off += (size_t)HID * DENSE * 2;     // 151.0 MB
    __half* z    = (__half*)(ws + off); off += (size_t)MROWS * HID * 2;    //  75.5 MB
    f16*    ApkHi = (f16*)(ws + off);  off += (size_t)MROWS * DENSE * 2;   //   9.4 MB
    f16*    Dpk  = (f16*)(ws + off);   off += (size_t)MROWS * DENSE * 4;   //  18.9 MB
    float*  h    = (float*)(ws + off); off += (size_t)MROWS * DENSE * 4;   //  18.9 MB
    float*  dbuf = (float*)(ws + off); off += (size_t)MROWS * DENSE * 4;   //  18.9 MB
    f16*    W1pk = (f16*)(ws + off);
    f16*    Wd2pk = (f16*)(ws + off);  off += (size_t)DENSE * DIM * 4;     //   9.4 MB
    f16*    xcpk = (f16*)(ws + off);   off += (size_t)MROWS * DIM * 4;     //   4.7 MB
    float*  tkv  = (float*)(ws + off); off += (size_t)MROWS * KSEL * 4;
    int*    tki  = (int*)(ws + off);   off += (size_t)MROWS * KSEL * 4;
    int*    candi = (int*)(ws + off);  off += (size_t)MROWS * CAP * 4;
    int*    candn = (int*)(ws + off);  off += (size_t)MROWS * 4;

    // xcpk = split(x - decoder_b2)
    xcpack_kernel<<<24 * MF_TOT / 4, 256, 0, stream>>>(x, dec_b2, xcpk);
    // W1pk = split(enc_w1)
    wpack_kernel<24><<<24 * 24 * 8 / 4, 256, 0, stream>>>(enc_w1, W1pk, 0);
    // h = gelu(xc @ enc_w1^T + b1)   (3-term, fp32-equivalent)
    mfma_nt_kernel<24, 1><<<dim3(12, 24), 256, 0, stream>>>(
        xcpk, W1pk, enc_b1, h, DENSE, 0);
    // ApkHi = fp16(h); Wpk = fp16(enc_w2)
    apackhi_kernel<<<96 * MF_TOT / 4, 256, 0, stream>>>(h, ApkHi);
    wpackhi_kernel<<<192 * 96 * 8 / 4, 256, 0, stream>>>(enc_w2, Wpk);
    // z ~= h @ enc_w2^T + b2  (fp16 out; BM=128, 3 blocks/CU, zero-tail grid)
    enc2v7_kernel<<<dim3(12, 192), 256, 0, stream>>>(ApkHi, Wpk, enc_b2, z);
    // w1t = transpose(decoder_w1) fp16 (overwrites Wpk — dead after enc2)
    transpose_w1_kernel<<<dim3(HID / 32, DENSE / 32), 256, 0, stream>>>(dec_w1, w1t);
    // radix-select candidate superset (>= NC) per row
    topksel_kernel<<<MROWS, 512, 0, stream>>>(z, candi, candn);
    // epsilon-band exact rescue (wave-parallel ranks) -> exact top-16 set
    resolve16_kernel<<<MROWS, 256, 0, stream>>>(
        z, h, enc_w2, enc_b2, candi, candn, tkv, tki);
    // d = gelu(sparse decode + b1) — coalesced gather of w1t rows (L3-resident)
    sparse_decode_kernel<<<MROWS, 256, 0, stream>>>(tkv, tki, w1t, dec_b1, dbuf);
    // Dpk = split(d)
    apack_kernel<96, 96><<<96 * 96 / 4, 256, 0, stream>>>(dbuf, Dpk);
    // Wd2pk = split(dec_w2)
    wpack_kernel<96><<<6 * 96 * 8 / 4, 256, 0, stream>>>(dec_w2, Wd2pk, 0);
    // out = d @ dec_w2^T + dec_b2   (3-term)
    mfma_nt_kernel<96, 2><<<dim3(12, 6), 256, 0, stream>>>(
        Dpk, Wd2pk, dec_b2, out, DIM, 0);
}

// Round 16
// 623.439 us; speedup vs baseline: 1.0624x; 1.0624x over previous
//
#include <hip/hip_runtime.h>
#include <hip/hip_fp16.h>

#define DIM 768
#define HID 24576
#define DENSE 3072
#define LL 24
#define MROWS 1536
#define KSEL 16
#define NC 24              // certified candidate rank (true top-16 in approx top-24)
#define CAP 40             // candidate capacity (NC + threshold ties)
#define MF_TOT 96          // MROWS/16
#define ENC2_NT 96         // DENSE/32 K-tiles for enc2 (BK=32)
#define DELTA 2e-3f        // band half-width >= 2x max |fp16-z - true z| (~5e-4)

typedef _Float16 f16;
typedef __attribute__((ext_vector_type(8))) _Float16 f16x8;
typedef __attribute__((ext_vector_type(4))) float f32x4;
typedef const __attribute__((address_space(1))) char* gcp;
typedef __attribute__((address_space(3))) char* lcp;

__device__ __forceinline__ float gelu_exact(float x) {
    return 0.5f * x * (1.0f + erff(x * 0.7071067811865476f));
}

// ---------------------------------------------------------- fp16 hi/lo split
__device__ __forceinline__ void split8(const float4& v0, const float4& v1,
                                       f16x8& hi, f16x8& lo) {
    float vv[8] = {v0.x, v0.y, v0.z, v0.w, v1.x, v1.y, v1.z, v1.w};
#pragma unroll
    for (int j = 0; j < 8; ++j) {
        f16 h = (f16)vv[j];
        hi[j] = h;
        lo[j] = (f16)((vv[j] - (float)h) * 2048.0f);
    }
}

// Fragment packing: chunk = 64 lanes x 16B; lane holds 8 halves for
// (row = base + (lane&15), k = ks*32 + (lane>>4)*8 + j). Same packing for A
// and W => K-slot permutation cancels inside MFMA.

// ---- hi+lo packs (3-term GEMM operands) ----
template <int KTOT, int RFTOT>
__global__ __launch_bounds__(256) void apack_kernel(
    const float* __restrict__ src, f16* __restrict__ dst) {
    int c = blockIdx.x * 4 + (threadIdx.x >> 6);
    int lane = threadIdx.x & 63;
    int rf = c % RFTOT, ks = c / RFTOT;
    int m = rf * 16 + (lane & 15);
    int k = ks * 32 + (lane >> 4) * 8;
    const float4* s = (const float4*)(src + (size_t)m * (KTOT * 32) + k);
    f16x8 hi, lo;
    split8(s[0], s[1], hi, lo);
    char* base = (char*)dst + (size_t)c * 2048 + lane * 16;
    *(f16x8*)base = hi;
    *(f16x8*)(base + 1024) = lo;
}

__global__ __launch_bounds__(256) void xcpack_kernel(
    const float* __restrict__ x, const float* __restrict__ b2,
    f16* __restrict__ dst) {
    int c = blockIdx.x * 4 + (threadIdx.x >> 6);
    int lane = threadIdx.x & 63;
    int rf = c % MF_TOT, ks = c / MF_TOT;
    int m = rf * 16 + (lane & 15);
    int k = ks * 32 + (lane >> 4) * 8;
    const float4* sx = (const float4*)(x + (size_t)m * DIM + k);
    const float4* sb = (const float4*)(b2 + (m % LL) * DIM + k);
    float4 v0 = sx[0], v1 = sx[1], b0 = sb[0], b1 = sb[1];
    v0.x -= b0.x; v0.y -= b0.y; v0.z -= b0.z; v0.w -= b0.w;
    v1.x -= b1.x; v1.y -= b1.y; v1.z -= b1.z; v1.w -= b1.w;
    f16x8 hi, lo;
    split8(v0, v1, hi, lo);
    char* base = (char*)dst + (size_t)c * 2048 + lane * 16;
    *(f16x8*)base = hi;
    *(f16x8*)(base + 1024) = lo;
}

template <int KTOT>
__global__ __launch_bounds__(256) void wpack_kernel(
    const float* __restrict__ src, f16* __restrict__ dst, int row0) {
    int c = blockIdx.x * 4 + (threadIdx.x >> 6);
    int lane = threadIdx.x & 63;
    int nf = c & 7; int t = c >> 3; int ks = t % KTOT; int nb = t / KTOT;
    int n = row0 + nb * 128 + nf * 16 + (lane & 15);
    int k = ks * 32 + (lane >> 4) * 8;
    const float4* s = (const float4*)(src + (size_t)n * (KTOT * 32) + k);
    f16x8 hi, lo;
    split8(s[0], s[1], hi, lo);
    char* base = (char*)dst + (size_t)c * 2048 + lane * 16;
    *(f16x8*)base = hi;
    *(f16x8*)(base + 1024) = lo;
}

// ---- hi-only packs (enc2 approx path) ----
__global__ __launch_bounds__(256) void apackhi_kernel(
    const float* __restrict__ src, f16* __restrict__ dst) {
    int c = blockIdx.x * 4 + (threadIdx.x >> 6);
    int lane = threadIdx.x & 63;
    int rf = c % MF_TOT, ks = c / MF_TOT;
    int m = rf * 16 + (lane & 15);
    int k = ks * 32 + (lane >> 4) * 8;
    const float4* s = (const float4*)(src + (size_t)m * DENSE + k);
    float4 v0 = s[0], v1 = s[1];
    float vv[8] = {v0.x, v0.y, v0.z, v0.w, v1.x, v1.y, v1.z, v1.w};
    f16x8 hi;
#pragma unroll
    for (int j = 0; j < 8; ++j) hi[j] = (f16)vv[j];
    *(f16x8*)((char*)dst + (size_t)c * 1024 + lane * 16) = hi;
}

__global__ __launch_bounds__(256) void wpackhi_kernel(
    const float* __restrict__ src, f16* __restrict__ dst) {
    int c = blockIdx.x * 4 + (threadIdx.x >> 6);
    int lane = threadIdx.x & 63;
    int nf = c & 7; int t = c >> 3; int ks = t % 96; int nb = t / 96;
    int n = nb * 128 + nf * 16 + (lane & 15);
    int k = ks * 32 + (lane >> 4) * 8;
    const float4* s = (const float4*)(src + (size_t)n * DENSE + k);
    float4 v0 = s[0], v1 = s[1];
    float vv[8] = {v0.x, v0.y, v0.z, v0.w, v1.x, v1.y, v1.z, v1.w};
    f16x8 hi;
#pragma unroll
    for (int j = 0; j < 8; ++j) hi[j] = (f16)vv[j];
    *(f16x8*)((char*)dst + (size_t)c * 1024 + lane * 16) = hi;
}

// --------------------------------------------- transpose decoder_w1 -> fp16
// src [DENSE][HID] fp32  ->  dst [HID][DENSE] fp16
__global__ __launch_bounds__(256) void transpose_w1_kernel(
    const float* __restrict__ src, __half* __restrict__ dst) {
    __shared__ float tile[32][33];
    const int c0 = blockIdx.x * 32;   // along HID
    const int r0 = blockIdx.y * 32;   // along DENSE
    const int tx = threadIdx.x & 31, ty = threadIdx.x >> 5;
#pragma unroll
    for (int i = 0; i < 32; i += 8)
        tile[ty + i][tx] = src[(size_t)(r0 + ty + i) * HID + c0 + tx];
    __syncthreads();
#pragma unroll
    for (int i = 0; i < 32; i += 8)
        dst[(size_t)(c0 + ty + i) * DENSE + r0 + tx] = __float2half(tile[tx][ty + i]);
}

// ------------------------------------------------- split-fp16 MFMA GEMM (NT)
// 3-term fp32-equivalent (enc1 EPI=1, dec2 EPI=2) — proven m97-style structure
template <int KTOT, int EPI>
__global__ __launch_bounds__(256, 2) void mfma_nt_kernel(
    const f16* __restrict__ Apk, const f16* __restrict__ Wpk,
    const float* __restrict__ bias, float* __restrict__ C,
    int N, int n0g) {
    __shared__ __align__(16) char lds[2][32768];
    const int tid = threadIdx.x;
    const int lane = tid & 63, wave = tid >> 6;
    const int mb = blockIdx.x, nb = blockIdx.y;
    const int wr = wave >> 1, wc = wave & 1;
    const char* ApkB = (const char*)Apk;
    const char* WpkB = (const char*)Wpk;

    f32x4 accH[4][4] = {}; f32x4 accL[4][4] = {};

    auto stage = [&](int buf, int ks) {
        const char* Ar = ApkB + (size_t)(ks * MF_TOT + mb * 8) * 2048;
        const char* Wr = WpkB + (size_t)(nb * KTOT + ks) * 16384;
#pragma unroll
        for (int q = 0; q < 8; ++q) {
            int c = wave * 8 + q;
            const char* src = (c < 16 ? Ar + c * 1024 : Wr + (c - 16) * 1024) + lane * 16;
            char* dst = &lds[buf][c * 1024];
            __builtin_amdgcn_global_load_lds((gcp)src, (lcp)dst, 16, 0, 0);
        }
    };

    stage(0, 0);
    for (int ks = 0; ks < KTOT; ++ks) {
        int cur = ks & 1;
        __syncthreads();
        if (ks + 1 < KTOT) stage(cur ^ 1, ks + 1);
        const char* Bf = lds[cur];
        f16x8 Ahi[4], Alo[4], Whi[4], Wlo[4];
#pragma unroll
        for (int i = 0; i < 4; ++i) {
            Ahi[i] = *(const f16x8*)(Bf + ((wr * 4 + i) * 2 + 0) * 1024 + lane * 16);
            Alo[i] = *(const f16x8*)(Bf + ((wr * 4 + i) * 2 + 1) * 1024 + lane * 16);
            Whi[i] = *(const f16x8*)(Bf + 16384 + ((wc * 4 + i) * 2 + 0) * 1024 + lane * 16);
            Wlo[i] = *(const f16x8*)(Bf + 16384 + ((wc * 4 + i) * 2 + 1) * 1024 + lane * 16);
        }
#pragma unroll
        for (int i = 0; i < 4; ++i)
#pragma unroll
            for (int j = 0; j < 4; ++j) {
                accH[i][j] = __builtin_amdgcn_mfma_f32_16x16x32_f16(Ahi[i], Whi[j], accH[i][j], 0, 0, 0);
                accL[i][j] = __builtin_amdgcn_mfma_f32_16x16x32_f16(Ahi[i], Wlo[j], accL[i][j], 0, 0, 0);
                accL[i][j] = __builtin_amdgcn_mfma_f32_16x16x32_f16(Alo[i], Whi[j], accL[i][j], 0, 0, 0);
            }
    }
    const int rbase = mb * 128 + wr * 64 + (lane >> 4) * 4;
    const int cb = n0g + nb * 128 + wc * 64 + (lane & 15);
#pragma unroll
    for (int j = 0; j < 4; ++j) {
        int col = cb + j * 16;
        float bn = (EPI == 2) ? 0.0f : bias[col];
#pragma unroll
        for (int i = 0; i < 4; ++i) {
#pragma unroll
            for (int e = 0; e < 4; ++e) {
                int row = rbase + i * 16 + e;
                float v = accH[i][j][e] + accL[i][j][e] * (1.0f / 2048.0f);
                if (EPI == 1)       v = gelu_exact(v + bn);
                else if (EPI == 0)  v += bn;
                else                v += bias[(row % LL) * N + col];
                C[(size_t)row * N + col] = v;
            }
        }
    }
}

// ---------------- enc2 v3 (FROZEN): 3-buffer / 1-barrier 256x128 fp16 MFMA
// z[m,n] ~= sum_k h[m,k]*w2[n,k] + b2[n]  (hi-term only, fp32 accum, fp16 out)
__global__ __launch_bounds__(512, 4) void enc2v3_kernel(
    const f16* __restrict__ Apk, const f16* __restrict__ Wpk,
    const float* __restrict__ b2, __half* __restrict__ z) {
    __shared__ __align__(16) char lds[3][24576];   // per buf: A 16KB | W 8KB
    const int tid = threadIdx.x;
    const int lane = tid & 63, wave = tid >> 6;
    // bijective XCD-chunked swizzle: 1152 blocks = 8 x 144
    int f = blockIdx.y * 6 + blockIdx.x;
    int ff = (f & 7) * 144 + (f >> 3);
    const int mb = ff % 6, nb = ff / 6;            // BM=256 (6), BN=128 (192)
    const int wr = wave >> 1, wc = wave & 1;       // 4M x 2N wave grid
    const char* ApkB = (const char*)Apk;
    const char* WpkB = (const char*)Wpk;
    f32x4 acc[4][4] = {};

    auto stage = [&](int t) {                      // tile t -> buf t%3 (3 loads)
        if (t >= ENC2_NT) return;
        char* dst = lds[t % 3];
        const char* Asrc = ApkB + ((size_t)t * MF_TOT + mb * 16) * 1024;
        __builtin_amdgcn_global_load_lds((gcp)(Asrc + tid * 16),
                                         (lcp)(dst + (tid & ~63) * 16), 16, 0, 0);
        __builtin_amdgcn_global_load_lds((gcp)(Asrc + tid * 16 + 8192),
                                         (lcp)(dst + (tid & ~63) * 16 + 8192), 16, 0, 0);
        const char* Wsrc = WpkB + ((size_t)nb * 96 + t) * 8192;
        __builtin_amdgcn_global_load_lds((gcp)(Wsrc + tid * 16),
                                         (lcp)(dst + 16384 + (tid & ~63) * 16), 16, 0, 0);
    };

    stage(0); stage(1);
    asm volatile("s_waitcnt vmcnt(3)" ::: "memory");   // tile0 landed, tile1 in flight
    __builtin_amdgcn_s_barrier();

    for (int t = 0; t < ENC2_NT; ++t) {
        const char* Bf = lds[t % 3];
        f16x8 Af[4], Wf[4];
#pragma unroll
        for (int i = 0; i < 4; ++i) {
            Af[i] = *(const f16x8*)(Bf + (wr * 4 + i) * 1024 + lane * 16);
            Wf[i] = *(const f16x8*)(Bf + 16384 + (wc * 4 + i) * 1024 + lane * 16);
        }
        stage(t + 2);          // targets buf[(t+2)%3]: not read this phase or next
        __builtin_amdgcn_s_setprio(1);
#pragma unroll
        for (int i = 0; i < 4; ++i)
#pragma unroll
            for (int j = 0; j < 4; ++j)
                acc[i][j] = __builtin_amdgcn_mfma_f32_16x16x32_f16(Af[i], Wf[j], acc[i][j], 0, 0, 0);
        __builtin_amdgcn_s_setprio(0);
        // boundary: t+1's loads (issued phase t-1) must land; t+2's 3 may fly
        if (t < ENC2_NT - 2)      asm volatile("s_waitcnt vmcnt(3)" ::: "memory");
        else if (t < ENC2_NT - 1) asm volatile("s_waitcnt vmcnt(0)" ::: "memory");
        if (t < ENC2_NT - 1) __builtin_amdgcn_s_barrier();
    }
    // epilogue: fp16 z
    const int rbase = mb * 256 + wr * 64 + (lane >> 4) * 4;
    const int cb = nb * 128 + wc * 64 + (lane & 15);
#pragma unroll
    for (int j = 0; j < 4; ++j) {
        int col = cb + j * 16;
        float bn = b2[col];
#pragma unroll
        for (int r = 0; r < 4; ++r)
#pragma unroll
            for (int e = 0; e < 4; ++e)
                z[(size_t)(rbase + r * 16 + e) * HID + col] = __float2half(acc[r][j][e] + bn);
    }
}

// ------------------- radix-select v2: two-level 256-bin, wave-0 shfl scans
// fp16 z -> u16 monotone keys in LDS; T = NC-th largest key (full 16-bit);
// emits index set {key >= T} + count. Same set semantics as v1, ~6 barriers.
__global__ __launch_bounds__(512) void topksel_kernel(
    const __half* __restrict__ z, int* __restrict__ candi, int* __restrict__ candn) {
    __shared__ unsigned short keys[HID];   // 48 KB
    __shared__ unsigned hist[256];         // 1 KB
    __shared__ int sB1, sA, sT, scnt;
    const int row = blockIdx.x, tid = threadIdx.x;
    const int lane = tid & 63, wave = tid >> 6;
    const uint4* zr = reinterpret_cast<const uint4*>(z + (size_t)row * HID);
    if (tid < 256) hist[tid] = 0;
    if (tid == 0) scnt = 0;
    __syncthreads();
    // pass 1: stage keys + 8-bit histogram (key[15:8])
#pragma unroll
    for (int i = 0; i < 6; ++i) {
        uint4 v = zr[tid + i * 512];
        unsigned w[4] = {v.x, v.y, v.z, v.w};
        int base = (tid + i * 512) * 8;
#pragma unroll
        for (int q = 0; q < 4; ++q)
#pragma unroll
            for (int s = 0; s < 2; ++s) {
                unsigned b = (w[q] >> (16 * s)) & 0xFFFFu;
                unsigned kk = b ^ ((b & 0x8000u) ? 0xFFFFu : 0x8000u);
                keys[base + q * 2 + s] = (unsigned short)kk;
                atomicAdd(&hist[kk >> 8], 1u);
            }
    }
    __syncthreads();
    // wave 0: descending cumulative scan, find bin of rank NC
    if (wave == 0) {
        const int b0 = 252 - 4 * lane;     // lane 0 owns top bins 252..255
        int part = 0;
#pragma unroll
        for (int j = 0; j < 4; ++j) part += (int)hist[b0 + j];
        int incl = part;
#pragma unroll
        for (int off = 1; off < 64; off <<= 1) {
            int v = __shfl_up(incl, off);
            if (lane >= off) incl += v;
        }
        int pre = incl - part;
        if (pre < NC && NC <= incl) {
            int cum = pre;
            for (int j = 3; j >= 0; --j) {     // walk bins high -> low
                int hh = (int)hist[b0 + j];
                if (cum + hh >= NC) { sB1 = b0 + j; sA = cum; break; }
                cum += hh;
            }
        }
    }
    __syncthreads();
    const int B1 = sB1, t2 = NC - sA;      // t2 >= 1
    __syncthreads();                       // all threads captured B1 before reset
    if (tid < 256) hist[tid] = 0;
    __syncthreads();
    // pass 2: 8-bit sub-histogram within bin B1 (keys re-scanned from LDS)
#pragma unroll
    for (int i = 0; i < 48; ++i) {
        unsigned kk = keys[tid + i * 512];
        if ((int)(kk >> 8) == B1) atomicAdd(&hist[kk & 0xFF], 1u);
    }
    __syncthreads();
    // wave 0: descending scan for rank t2 within the sub-bins
    if (wave == 0) {
        const int b0 = 252 - 4 * lane;
        int part = 0;
#pragma unroll
        for (int j = 0; j < 4; ++j) part += (int)hist[b0 + j];
        int incl = part;
#pragma unroll
        for (int off = 1; off < 64; off <<= 1) {
            int v = __shfl_up(incl, off);
            if (lane >= off) incl += v;
        }
        int pre = incl - part;
        if (pre < t2 && t2 <= incl) {
            int cum = pre;
            for (int j = 3; j >= 0; --j) {
                int hh = (int)hist[b0 + j];
                if (cum + hh >= t2) { sT = (B1 << 8) | (b0 + j); break; }
                cum += hh;
            }
        }
    }
    __syncthreads();
    const unsigned T = (unsigned)sT;
    // pass 3: compact indices with key >= T
#pragma unroll
    for (int i = 0; i < 48; ++i) {
        int idx = tid + i * 512;
        if ((unsigned)keys[idx] >= T) {
            int p = atomicAdd(&scnt, 1);
            if (p < CAP) candi[(size_t)row * CAP + p] = idx;
        }
    }
    __syncthreads();
    if (tid == 0) candn[row] = min(scnt, CAP);
}

// ----------------- epsilon-band rescue v2: fully wave-parallel ranking
// approx values av from fp16 z (|av - true| <= ~5e-4 << DELTA/2).
// Wave 0 holds all <=40 candidates in lanes; all-pairs shfl ranking gives
// v16 and final ranks. Band members (|av-v16|<=DELTA) get exact fp32 dots.
__global__ __launch_bounds__(256) void resolve16_kernel(
    const __half* __restrict__ z, const float* __restrict__ h,
    const float* __restrict__ w2, const float* __restrict__ b2,
    const int* __restrict__ candi, const int* __restrict__ candn,
    float* __restrict__ tkv, int* __restrict__ tki) {
    const int row = blockIdx.x, tid = threadIdx.x;
    const int lane = tid & 63, wave = tid >> 6;
    __shared__ float hs[DENSE];        // 12 KB
    __shared__ float av[64];
    __shared__ int ci[64];
    __shared__ int bnd[CAP];
    __shared__ int nb_s;
    const int cnt = candn[row];
    // all threads stage h row
    const float4* hr = reinterpret_cast<const float4*>(h + (size_t)row * DENSE);
#pragma unroll
    for (int j = 0; j < 3; ++j)
        reinterpret_cast<float4*>(hs)[tid + j * 256] = hr[tid + j * 256];
    // wave 0: load candidates into lanes, rank via all-pairs shuffles
    if (wave == 0) {
        float myv = -1e30f;
        int myi = 0x7fffffff;
        if (lane < cnt) {
            myi = candi[(size_t)row * CAP + lane];
            myv = __half2float(z[(size_t)row * HID + myi]);
        }
        int rank = 0;
#pragma unroll
        for (int o = 0; o < CAP; ++o) {
            float ov = __shfl(myv, o);
            int oi = __shfl(myi, o);
            rank += ((ov > myv) || (ov == myv && oi < myi)) ? 1 : 0;
        }
        // v16 = value of the unique lane with rank 15 (cnt >= NC > 16)
        unsigned long long m15 = __ballot(rank == 15);
        int sl = (int)__builtin_ctzll(m15);
        float v16 = __shfl(myv, sl);
        bool band = (lane < cnt) && (fabsf(myv - v16) <= DELTA);
        unsigned long long bm = __ballot(band);
        if (lane == 0) nb_s = (int)__popcll(bm);
        if (band) {
            int p = (int)__popcll(bm & ((1ull << lane) - 1ull));
            bnd[p] = lane;
        }
        av[lane] = myv;
        ci[lane] = myi;
    }
    __syncthreads();
    // exact fp32 dots for band members (one wave each; nb typically ~2)
    const int nbn = nb_s;
    for (int b = wave; b < nbn; b += 4) {
        int c = bnd[b];
        int n = ci[c];
        const float4* wr = reinterpret_cast<const float4*>(w2 + (size_t)n * DENSE);
        float p = 0.0f;
#pragma unroll
        for (int j = 0; j < 12; ++j) {
            float4 a = reinterpret_cast<const float4*>(hs)[lane + j * 64];
            float4 w = wr[lane + j * 64];
            p += a.x * w.x + a.y * w.y + a.z * w.z + a.w * w.w;
        }
#pragma unroll
        for (int off = 32; off >= 1; off >>= 1) p += __shfl_down(p, off);
        if (lane == 0) av[c] = p + b2[n];   // replace approx with exact
    }
    __syncthreads();
    // wave 0: final rank over mixed values, scatter rank<16 directly
    if (wave == 0) {
        float v = av[lane];
        int idx = ci[lane];
        int rank = 0;
#pragma unroll
        for (int o = 0; o < CAP; ++o) {
            float ov = __shfl(v, o);
            int oi = __shfl(idx, o);
            rank += ((ov > v) || (ov == v && oi < idx)) ? 1 : 0;
        }
        if (lane < cnt && rank < KSEL) {
            tkv[row * KSEL + rank] = fmaxf(v, 0.0f);   // act_fn = ReLU
            tki[row * KSEL + rank] = idx;
        }
    }
}

// ------------------------------------------------------------ sparse decode
// block row: d[row,:] = gelu( sum_k val_k * w1t[idx_k, :] + b1 )  (coalesced)
__global__ __launch_bounds__(256) void sparse_decode_kernel(
    const float* __restrict__ tkv, const int* __restrict__ tki,
    const __half* __restrict__ w1t, const float* __restrict__ b1,
    float* __restrict__ D) {
    const int row = blockIdx.x, tid = threadIdx.x;
    __shared__ float sv[KSEL];
    __shared__ int si[KSEL];
    if (tid < KSEL) { sv[tid] = tkv[row * KSEL + tid]; si[tid] = tki[row * KSEL + tid]; }
    __syncthreads();
    float2 acc[6] = {};
#pragma unroll 1
    for (int k = 0; k < KSEL; ++k) {
        const float v = sv[k];
        const __half2* wr = reinterpret_cast<const __half2*>(w1t + (size_t)si[k] * DENSE);
#pragma unroll
        for (int j = 0; j < 6; ++j) {
            float2 f = __half22float2(wr[tid + j * 256]);
            acc[j].x = fmaf(v, f.x, acc[j].x);
            acc[j].y = fmaf(v, f.y, acc[j].y);
        }
    }
#pragma unroll
    for (int j = 0; j < 6; ++j) {
        int dd = (tid + j * 256) * 2;
        D[(size_t)row * DENSE + dd]     = gelu_exact(acc[j].x + b1[dd]);
        D[(size_t)row * DENSE + dd + 1] = gelu_exact(acc[j].y + b1[dd + 1]);
    }
}

// ---------------------------------------------------------------- launch
extern "C" void kernel_launch(void* const* d_in, const int* in_sizes, int n_in,
                              void* d_out, int out_size, void* d_ws, size_t ws_size,
                              hipStream_t stream) {
    const float* x      = (const float*)d_in[0];
    const float* enc_w1 = (const float*)d_in[1];
    const float* enc_b1 = (const float*)d_in[2];
    const float* enc_w2 = (const float*)d_in[3];
    const float* enc_b2 = (const float*)d_in[4];
    const float* dec_w1 = (const float*)d_in[5];
    const float* dec_b1 = (const float*)d_in[6];
    const float* dec_w2 = (const float*)d_in[7];
    const float* dec_b2 = (const float*)d_in[8];
    float* out = (float*)d_out;

    char* ws = (char*)d_ws;
    size_t off = 0;
    // region1: Wpk (enc2 W hi-only) -> later w1t (both 151.0 MB; Wpk dead after enc2)
    f16*    Wpk = (f16*)(ws + off);
    __half* w1t = (__half*)(ws + off); off += (size_t)HID * DENSE * 2;     // 151.0 MB
    __half* z    = (__half*)(ws + off); off += (size_t)MROWS * HID * 2;    //  75.5 MB
    f16*    ApkHi = (f16*)(ws + off);  off += (size_t)MROWS * DENSE * 2;   //   9.4 MB
    f16*    Dpk  = (f16*)(ws + off);   off += (size_t)MROWS * DENSE * 4;   //  18.9 MB
    float*  h    = (float*)(ws + off); off += (size_t)MROWS * DENSE * 4;   //  18.9 MB
    float*  dbuf = (float*)(ws + off); off += (size_t)MROWS * DENSE * 4;   //  18.9 MB
    f16*    W1pk = (f16*)(ws + off);
    f16*    Wd2pk = (f16*)(ws + off);  off += (size_t)DENSE * DIM * 4;     //   9.4 MB
    f16*    xcpk = (f16*)(ws + off);   off += (size_t)MROWS * DIM * 4;     //   4.7 MB
    float*  tkv  = (float*)(ws + off); off += (size_t)MROWS * KSEL * 4;
    int*    tki  = (int*)(ws + off);   off += (size_t)MROWS * KSEL * 4;
    int*    candi = (int*)(ws + off);  off += (size_t)MROWS * CAP * 4;
    int*    candn = (int*)(ws + off);  off += (size_t)MROWS * 4;

    // xcpk = split(x - decoder_b2)
    xcpack_kernel<<<24 * MF_TOT / 4, 256, 0, stream>>>(x, dec_b2, xcpk);
    // W1pk = split(enc_w1)
    wpack_kernel<24><<<24 * 24 * 8 / 4, 256, 0, stream>>>(enc_w1, W1pk, 0);
    // h = gelu(xc @ enc_w1^T + b1)   (3-term, fp32-equivalent)
    mfma_nt_kernel<24, 1><<<dim3(12, 24), 256, 0, stream>>>(
        xcpk, W1pk, enc_b1, h, DENSE, 0);
    // ApkHi = fp16(h); Wpk = fp16(enc_w2)
    apackhi_kernel<<<96 * MF_TOT / 4, 256, 0, stream>>>(h, ApkHi);
    wpackhi_kernel<<<192 * 96 * 8 / 4, 256, 0, stream>>>(enc_w2, Wpk);
    // z ~= h @ enc_w2^T + b2  (fp16 out; 3-buf 1-barrier pipeline, FROZEN v3)
    enc2v3_kernel<<<dim3(6, 192), 512, 0, stream>>>(ApkHi, Wpk, enc_b2, z);
    // w1t = transpose(decoder_w1) fp16 (overwrites Wpk — dead after enc2)
    transpose_w1_kernel<<<dim3(HID / 32, DENSE / 32), 256, 0, stream>>>(dec_w1, w1t);
    // radix-select candidate superset (>= NC) per row — two-level 256-bin
    topksel_kernel<<<MROWS, 512, 0, stream>>>(z, candi, candn);
    // epsilon-band exact rescue (wave-parallel ranks) -> exact top-16 set
    resolve16_kernel<<<MROWS, 256, 0, stream>>>(
        z, h, enc_w2, enc_b2, candi, candn, tkv, tki);
    // d = gelu(sparse decode + b1) — coalesced gather of w1t rows (L3-resident)
    sparse_decode_kernel<<<MROWS, 256, 0, stream>>>(tkv, tki, w1t, dec_b1, dbuf);
    // Dpk = split(d)
    apack_kernel<96, 96><<<96 * 96 / 4, 256, 0, stream>>>(dbuf, Dpk);
    // Wd2pk = split(dec_w2)
    wpack_kernel<96><<<6 * 96 * 8 / 4, 256, 0, stream>>>(dec_w2, Wd2pk, 0);
    // out = d @ dec_w2^T + dec_b2   (3-term)
    mfma_nt_kernel<96, 2><<<dim3(12, 6), 256, 0, stream>>>(
        Dpk, Wd2pk, dec_b2, out, DIM, 0);
}

// Round 17
// 587.798 us; speedup vs baseline: 1.1269x; 1.0606x over previous
//
#include <hip/hip_runtime.h>
#include <hip/hip_fp16.h>

#define DIM 768
#define HID 24576
#define DENSE 3072
#define LL 24
#define MROWS 1536
#define KSEL 16
#define NC 24              // certified candidate rank (true top-16 in approx top-24)
#define CAP 40             // candidate capacity (NC + threshold ties)
#define MF_TOT 96          // MROWS/16
#define ENC2_NT 96         // DENSE/32 K-tiles for enc2 (BK=32)
#define DELTA 2e-3f        // band half-width >= 2x max |fp16-z - true z| (~5e-4)

typedef _Float16 f16;
typedef __attribute__((ext_vector_type(8))) _Float16 f16x8;
typedef __attribute__((ext_vector_type(4))) float f32x4;
typedef const __attribute__((address_space(1))) char* gcp;
typedef __attribute__((address_space(3))) char* lcp;

__device__ __forceinline__ float gelu_exact(float x) {
    return 0.5f * x * (1.0f + erff(x * 0.7071067811865476f));
}

// ---------------------------------------------------------- fp16 hi/lo split
__device__ __forceinline__ void split8(const float4& v0, const float4& v1,
                                       f16x8& hi, f16x8& lo) {
    float vv[8] = {v0.x, v0.y, v0.z, v0.w, v1.x, v1.y, v1.z, v1.w};
#pragma unroll
    for (int j = 0; j < 8; ++j) {
        f16 h = (f16)vv[j];
        hi[j] = h;
        lo[j] = (f16)((vv[j] - (float)h) * 2048.0f);
    }
}

// Fragment packing: chunk = 64 lanes x 16B; lane holds 8 halves for
// (row = base + (lane&15), k = ks*32 + (lane>>4)*8 + j). Same packing for A
// and W => K-slot permutation cancels inside MFMA.

// ---- hi+lo packs (3-term GEMM operands) ----
template <int KTOT, int RFTOT>
__global__ __launch_bounds__(256) void apack_kernel(
    const float* __restrict__ src, f16* __restrict__ dst) {
    int c = blockIdx.x * 4 + (threadIdx.x >> 6);
    int lane = threadIdx.x & 63;
    int rf = c % RFTOT, ks = c / RFTOT;
    int m = rf * 16 + (lane & 15);
    int k = ks * 32 + (lane >> 4) * 8;
    const float4* s = (const float4*)(src + (size_t)m * (KTOT * 32) + k);
    f16x8 hi, lo;
    split8(s[0], s[1], hi, lo);
    char* base = (char*)dst + (size_t)c * 2048 + lane * 16;
    *(f16x8*)base = hi;
    *(f16x8*)(base + 1024) = lo;
}

// prep1: blocks [0,576) = xcpack (x - dec_b2, hi/lo); [576,1728) = wpack24(enc_w1)
__global__ __launch_bounds__(256) void prep1_kernel(
    const float* __restrict__ x, const float* __restrict__ b2,
    f16* __restrict__ xcpk,
    const float* __restrict__ w1src, f16* __restrict__ W1pk) {
    int lane = threadIdx.x & 63;
    if (blockIdx.x < 576) {
        int c = blockIdx.x * 4 + (threadIdx.x >> 6);
        int rf = c % MF_TOT, ks = c / MF_TOT;
        int m = rf * 16 + (lane & 15);
        int k = ks * 32 + (lane >> 4) * 8;
        const float4* sx = (const float4*)(x + (size_t)m * DIM + k);
        const float4* sb = (const float4*)(b2 + (m % LL) * DIM + k);
        float4 v0 = sx[0], v1 = sx[1], b0 = sb[0], b1 = sb[1];
        v0.x -= b0.x; v0.y -= b0.y; v0.z -= b0.z; v0.w -= b0.w;
        v1.x -= b1.x; v1.y -= b1.y; v1.z -= b1.z; v1.w -= b1.w;
        f16x8 hi, lo;
        split8(v0, v1, hi, lo);
        char* base = (char*)xcpk + (size_t)c * 2048 + lane * 16;
        *(f16x8*)base = hi;
        *(f16x8*)(base + 1024) = lo;
    } else {
        int c = (blockIdx.x - 576) * 4 + (threadIdx.x >> 6);
        int nf = c & 7; int t = c >> 3; int ks = t % 24; int nb = t / 24;
        int n = nb * 128 + nf * 16 + (lane & 15);
        int k = ks * 32 + (lane >> 4) * 8;
        const float4* s = (const float4*)(w1src + (size_t)n * DIM + k);
        f16x8 hi, lo;
        split8(s[0], s[1], hi, lo);
        char* base = (char*)W1pk + (size_t)c * 2048 + lane * 16;
        *(f16x8*)base = hi;
        *(f16x8*)(base + 1024) = lo;
    }
}

template <int KTOT>
__global__ __launch_bounds__(256) void wpack_kernel(
    const float* __restrict__ src, f16* __restrict__ dst, int row0) {
    int c = blockIdx.x * 4 + (threadIdx.x >> 6);
    int lane = threadIdx.x & 63;
    int nf = c & 7; int t = c >> 3; int ks = t % KTOT; int nb = t / KTOT;
    int n = row0 + nb * 128 + nf * 16 + (lane & 15);
    int k = ks * 32 + (lane >> 4) * 8;
    const float4* s = (const float4*)(src + (size_t)n * (KTOT * 32) + k);
    f16x8 hi, lo;
    split8(s[0], s[1], hi, lo);
    char* base = (char*)dst + (size_t)c * 2048 + lane * 16;
    *(f16x8*)base = hi;
    *(f16x8*)(base + 1024) = lo;
}

// prep2: blocks [0,2304) = apackhi(h); [2304,39168) = wpackhi(enc_w2)
__global__ __launch_bounds__(256) void prep2_kernel(
    const float* __restrict__ h, f16* __restrict__ ApkHi,
    const float* __restrict__ w2, f16* __restrict__ Wpk) {
    int lane = threadIdx.x & 63;
    if (blockIdx.x < 2304) {
        int c = blockIdx.x * 4 + (threadIdx.x >> 6);
        int rf = c % MF_TOT, ks = c / MF_TOT;
        int m = rf * 16 + (lane & 15);
        int k = ks * 32 + (lane >> 4) * 8;
        const float4* s = (const float4*)(h + (size_t)m * DENSE + k);
        float4 v0 = s[0], v1 = s[1];
        float vv[8] = {v0.x, v0.y, v0.z, v0.w, v1.x, v1.y, v1.z, v1.w};
        f16x8 hi;
#pragma unroll
        for (int j = 0; j < 8; ++j) hi[j] = (f16)vv[j];
        *(f16x8*)((char*)ApkHi + (size_t)c * 1024 + lane * 16) = hi;
    } else {
        int c = (blockIdx.x - 2304) * 4 + (threadIdx.x >> 6);
        int nf = c & 7; int t = c >> 3; int ks = t % 96; int nb = t / 96;
        int n = nb * 128 + nf * 16 + (lane & 15);
        int k = ks * 32 + (lane >> 4) * 8;
        const float4* s = (const float4*)(w2 + (size_t)n * DENSE + k);
        float4 v0 = s[0], v1 = s[1];
        float vv[8] = {v0.x, v0.y, v0.z, v0.w, v1.x, v1.y, v1.z, v1.w};
        f16x8 hi;
#pragma unroll
        for (int j = 0; j < 8; ++j) hi[j] = (f16)vv[j];
        *(f16x8*)((char*)Wpk + (size_t)c * 1024 + lane * 16) = hi;
    }
}

// --------------------------------------------- transpose decoder_w1 -> fp16
// src [DENSE][HID] fp32  ->  dst [HID][DENSE] fp16
__global__ __launch_bounds__(256) void transpose_w1_kernel(
    const float* __restrict__ src, __half* __restrict__ dst) {
    __shared__ float tile[32][33];
    const int c0 = blockIdx.x * 32;   // along HID
    const int r0 = blockIdx.y * 32;   // along DENSE
    const int tx = threadIdx.x & 31, ty = threadIdx.x >> 5;
#pragma unroll
    for (int i = 0; i < 32; i += 8)
        tile[ty + i][tx] = src[(size_t)(r0 + ty + i) * HID + c0 + tx];
    __syncthreads();
#pragma unroll
    for (int i = 0; i < 32; i += 8)
        dst[(size_t)(c0 + ty + i) * DENSE + r0 + tx] = __float2half(tile[tx][ty + i]);
}

// ------------------------------------------------- split-fp16 MFMA GEMM (NT)
// 3-term fp32-equivalent (enc1 EPI=1) — proven m97-style structure
template <int KTOT, int EPI>
__global__ __launch_bounds__(256, 2) void mfma_nt_kernel(
    const f16* __restrict__ Apk, const f16* __restrict__ Wpk,
    const float* __restrict__ bias, float* __restrict__ C,
    int N, int n0g) {
    __shared__ __align__(16) char lds[2][32768];
    const int tid = threadIdx.x;
    const int lane = tid & 63, wave = tid >> 6;
    const int mb = blockIdx.x, nb = blockIdx.y;
    const int wr = wave >> 1, wc = wave & 1;
    const char* ApkB = (const char*)Apk;
    const char* WpkB = (const char*)Wpk;

    f32x4 accH[4][4] = {}; f32x4 accL[4][4] = {};

    auto stage = [&](int buf, int ks) {
        const char* Ar = ApkB + (size_t)(ks * MF_TOT + mb * 8) * 2048;
        const char* Wr = WpkB + (size_t)(nb * KTOT + ks) * 16384;
#pragma unroll
        for (int q = 0; q < 8; ++q) {
            int c = wave * 8 + q;
            const char* src = (c < 16 ? Ar + c * 1024 : Wr + (c - 16) * 1024) + lane * 16;
            char* dst = &lds[buf][c * 1024];
            __builtin_amdgcn_global_load_lds((gcp)src, (lcp)dst, 16, 0, 0);
        }
    };

    stage(0, 0);
    for (int ks = 0; ks < KTOT; ++ks) {
        int cur = ks & 1;
        __syncthreads();
        if (ks + 1 < KTOT) stage(cur ^ 1, ks + 1);
        const char* Bf = lds[cur];
        f16x8 Ahi[4], Alo[4], Whi[4], Wlo[4];
#pragma unroll
        for (int i = 0; i < 4; ++i) {
            Ahi[i] = *(const f16x8*)(Bf + ((wr * 4 + i) * 2 + 0) * 1024 + lane * 16);
            Alo[i] = *(const f16x8*)(Bf + ((wr * 4 + i) * 2 + 1) * 1024 + lane * 16);
            Whi[i] = *(const f16x8*)(Bf + 16384 + ((wc * 4 + i) * 2 + 0) * 1024 + lane * 16);
            Wlo[i] = *(const f16x8*)(Bf + 16384 + ((wc * 4 + i) * 2 + 1) * 1024 + lane * 16);
        }
#pragma unroll
        for (int i = 0; i < 4; ++i)
#pragma unroll
            for (int j = 0; j < 4; ++j) {
                accH[i][j] = __builtin_amdgcn_mfma_f32_16x16x32_f16(Ahi[i], Whi[j], accH[i][j], 0, 0, 0);
                accL[i][j] = __builtin_amdgcn_mfma_f32_16x16x32_f16(Ahi[i], Wlo[j], accL[i][j], 0, 0, 0);
                accL[i][j] = __builtin_amdgcn_mfma_f32_16x16x32_f16(Alo[i], Whi[j], accL[i][j], 0, 0, 0);
            }
    }
    const int rbase = mb * 128 + wr * 64 + (lane >> 4) * 4;
    const int cb = n0g + nb * 128 + wc * 64 + (lane & 15);
#pragma unroll
    for (int j = 0; j < 4; ++j) {
        int col = cb + j * 16;
        float bn = (EPI == 2) ? 0.0f : bias[col];
#pragma unroll
        for (int i = 0; i < 4; ++i) {
#pragma unroll
            for (int e = 0; e < 4; ++e) {
                int row = rbase + i * 16 + e;
                float v = accH[i][j][e] + accL[i][j][e] * (1.0f / 2048.0f);
                if (EPI == 1)       v = gelu_exact(v + bn);
                else if (EPI == 0)  v += bn;
                else                v += bias[(row % LL) * N + col];
                C[(size_t)row * N + col] = v;
            }
        }
    }
}

// --------- mfma64: 64x64-tile 3-term GEMM for dec2 (EPI=2), 288 blocks
// 4 waves as 2x2, each 32x32; double-buffered 2x16KB; reuses Dpk/Wd2pk layouts.
__global__ __launch_bounds__(256, 4) void mfma64_kernel(
    const f16* __restrict__ Apk, const f16* __restrict__ Wpk,
    const float* __restrict__ bias, float* __restrict__ C) {
    __shared__ __align__(16) char lds[2][16384];   // A 8KB | W 8KB
    const int tid = threadIdx.x;
    const int lane = tid & 63, wave = tid >> 6;
    const int mb = blockIdx.x, nbi = blockIdx.y;   // 24 x 12
    const int wr = wave >> 1, wc = wave & 1;
    const char* ApkB = (const char*)Apk;
    const char* WpkB = (const char*)Wpk;

    f32x4 accH[2][2] = {}; f32x4 accL[2][2] = {};

    auto stage = [&](int buf, int ks) {
        // A: 4 contiguous chunks (rf = mb*4 .. +3), 8 KB
        const char* Ar = ApkB + (size_t)(ks * 96 + mb * 4) * 2048;
        // W: 4 contiguous chunks at ((nbi>>1)*96 + ks)*8 + (nbi&1)*4, 8 KB
        const char* Wr = WpkB + (((size_t)(nbi >> 1) * 96 + ks) * 8 + (nbi & 1) * 4) * 2048;
#pragma unroll
        for (int q = 0; q < 2; ++q) {
            __builtin_amdgcn_global_load_lds(
                (gcp)(Ar + tid * 16 + q * 4096),
                (lcp)(&lds[buf][0] + (tid & ~63) * 16 + q * 4096), 16, 0, 0);
            __builtin_amdgcn_global_load_lds(
                (gcp)(Wr + tid * 16 + q * 4096),
                (lcp)(&lds[buf][8192] + (tid & ~63) * 16 + q * 4096), 16, 0, 0);
        }
    };

    stage(0, 0);
    for (int ks = 0; ks < 96; ++ks) {
        int cur = ks & 1;
        __syncthreads();
        if (ks + 1 < 96) stage(cur ^ 1, ks + 1);
        const char* Bf = lds[cur];
        f16x8 Ahi[2], Alo[2], Whi[2], Wlo[2];
#pragma unroll
        for (int i = 0; i < 2; ++i) {
            Ahi[i] = *(const f16x8*)(Bf + (wr * 2 + i) * 2048 + lane * 16);
            Alo[i] = *(const f16x8*)(Bf + (wr * 2 + i) * 2048 + 1024 + lane * 16);
            Whi[i] = *(const f16x8*)(Bf + 8192 + (wc * 2 + i) * 2048 + lane * 16);
            Wlo[i] = *(const f16x8*)(Bf + 8192 + (wc * 2 + i) * 2048 + 1024 + lane * 16);
        }
#pragma unroll
        for (int i = 0; i < 2; ++i)
#pragma unroll
            for (int j = 0; j < 2; ++j) {
                accH[i][j] = __builtin_amdgcn_mfma_f32_16x16x32_f16(Ahi[i], Whi[j], accH[i][j], 0, 0, 0);
                accL[i][j] = __builtin_amdgcn_mfma_f32_16x16x32_f16(Ahi[i], Wlo[j], accL[i][j], 0, 0, 0);
                accL[i][j] = __builtin_amdgcn_mfma_f32_16x16x32_f16(Alo[i], Whi[j], accL[i][j], 0, 0, 0);
            }
    }
    const int rbase = mb * 64 + wr * 32 + (lane >> 4) * 4;
    const int cb = nbi * 64 + wc * 32 + (lane & 15);
#pragma unroll
    for (int j = 0; j < 2; ++j) {
        int col = cb + j * 16;
#pragma unroll
        for (int i = 0; i < 2; ++i) {
#pragma unroll
            for (int e = 0; e < 4; ++e) {
                int row = rbase + i * 16 + e;
                float v = accH[i][j][e] + accL[i][j][e] * (1.0f / 2048.0f)
                        + bias[(row % LL) * DIM + col];
                C[(size_t)row * DIM + col] = v;
            }
        }
    }
}

// ---------------- enc2 v3 (FROZEN): 3-buffer / 1-barrier 256x128 fp16 MFMA
__global__ __launch_bounds__(512, 4) void enc2v3_kernel(
    const f16* __restrict__ Apk, const f16* __restrict__ Wpk,
    const float* __restrict__ b2, __half* __restrict__ z) {
    __shared__ __align__(16) char lds[3][24576];   // per buf: A 16KB | W 8KB
    const int tid = threadIdx.x;
    const int lane = tid & 63, wave = tid >> 6;
    // bijective XCD-chunked swizzle: 1152 blocks = 8 x 144
    int f = blockIdx.y * 6 + blockIdx.x;
    int ff = (f & 7) * 144 + (f >> 3);
    const int mb = ff % 6, nb = ff / 6;            // BM=256 (6), BN=128 (192)
    const int wr = wave >> 1, wc = wave & 1;       // 4M x 2N wave grid
    const char* ApkB = (const char*)Apk;
    const char* WpkB = (const char*)Wpk;
    f32x4 acc[4][4] = {};

    auto stage = [&](int t) {                      // tile t -> buf t%3 (3 loads)
        if (t >= ENC2_NT) return;
        char* dst = lds[t % 3];
        const char* Asrc = ApkB + ((size_t)t * MF_TOT + mb * 16) * 1024;
        __builtin_amdgcn_global_load_lds((gcp)(Asrc + tid * 16),
                                         (lcp)(dst + (tid & ~63) * 16), 16, 0, 0);
        __builtin_amdgcn_global_load_lds((gcp)(Asrc + tid * 16 + 8192),
                                         (lcp)(dst + (tid & ~63) * 16 + 8192), 16, 0, 0);
        const char* Wsrc = WpkB + ((size_t)nb * 96 + t) * 8192;
        __builtin_amdgcn_global_load_lds((gcp)(Wsrc + tid * 16),
                                         (lcp)(dst + 16384 + (tid & ~63) * 16), 16, 0, 0);
    };

    stage(0); stage(1);
    asm volatile("s_waitcnt vmcnt(3)" ::: "memory");   // tile0 landed, tile1 in flight
    __builtin_amdgcn_s_barrier();

    for (int t = 0; t < ENC2_NT; ++t) {
        const char* Bf = lds[t % 3];
        f16x8 Af[4], Wf[4];
#pragma unroll
        for (int i = 0; i < 4; ++i) {
            Af[i] = *(const f16x8*)(Bf + (wr * 4 + i) * 1024 + lane * 16);
            Wf[i] = *(const f16x8*)(Bf + 16384 + (wc * 4 + i) * 1024 + lane * 16);
        }
        stage(t + 2);          // targets buf[(t+2)%3]: not read this phase or next
        __builtin_amdgcn_s_setprio(1);
#pragma unroll
        for (int i = 0; i < 4; ++i)
#pragma unroll
            for (int j = 0; j < 4; ++j)
                acc[i][j] = __builtin_amdgcn_mfma_f32_16x16x32_f16(Af[i], Wf[j], acc[i][j], 0, 0, 0);
        __builtin_amdgcn_s_setprio(0);
        // boundary: t+1's loads (issued phase t-1) must land; t+2's 3 may fly
        if (t < ENC2_NT - 2)      asm volatile("s_waitcnt vmcnt(3)" ::: "memory");
        else if (t < ENC2_NT - 1) asm volatile("s_waitcnt vmcnt(0)" ::: "memory");
        if (t < ENC2_NT - 1) __builtin_amdgcn_s_barrier();
    }
    // epilogue: fp16 z
    const int rbase = mb * 256 + wr * 64 + (lane >> 4) * 4;
    const int cb = nb * 128 + wc * 64 + (lane & 15);
#pragma unroll
    for (int j = 0; j < 4; ++j) {
        int col = cb + j * 16;
        float bn = b2[col];
#pragma unroll
        for (int r = 0; r < 4; ++r)
#pragma unroll
            for (int e = 0; e < 4; ++e)
                z[(size_t)(rbase + r * 16 + e) * HID + col] = __float2half(acc[r][j][e] + bn);
    }
}

// ------------------- radix-select v3: two-level 256-bin, x4 replicated hist
__global__ __launch_bounds__(512) void topksel_kernel(
    const __half* __restrict__ z, int* __restrict__ candi, int* __restrict__ candn) {
    __shared__ unsigned short keys[HID];   // 48 KB
    __shared__ unsigned hist[4][256];      // 4 KB (x4 replicated: less contention)
    __shared__ int sB1, sA, sT, scnt;
    const int row = blockIdx.x, tid = threadIdx.x;
    const int lane = tid & 63, wave = tid >> 6;
    const int hrep = wave & 3;
    const uint4* zr = reinterpret_cast<const uint4*>(z + (size_t)row * HID);
    if (tid < 256) { hist[0][tid] = 0; hist[1][tid] = 0; hist[2][tid] = 0; hist[3][tid] = 0; }
    if (tid == 0) scnt = 0;
    __syncthreads();
    // pass 1: stage keys + 8-bit histogram (key[15:8])
#pragma unroll
    for (int i = 0; i < 6; ++i) {
        uint4 v = zr[tid + i * 512];
        unsigned w[4] = {v.x, v.y, v.z, v.w};
        int base = (tid + i * 512) * 8;
#pragma unroll
        for (int q = 0; q < 4; ++q)
#pragma unroll
            for (int s = 0; s < 2; ++s) {
                unsigned b = (w[q] >> (16 * s)) & 0xFFFFu;
                unsigned kk = b ^ ((b & 0x8000u) ? 0xFFFFu : 0x8000u);
                keys[base + q * 2 + s] = (unsigned short)kk;
                atomicAdd(&hist[hrep][kk >> 8], 1u);
            }
    }
    __syncthreads();
    // wave 0: descending cumulative scan, find bin of rank NC
    if (wave == 0) {
        const int b0 = 252 - 4 * lane;     // lane 0 owns top bins 252..255
        int bc[4];
#pragma unroll
        for (int j = 0; j < 4; ++j)
            bc[j] = (int)(hist[0][b0 + j] + hist[1][b0 + j] + hist[2][b0 + j] + hist[3][b0 + j]);
        int part = bc[0] + bc[1] + bc[2] + bc[3];
        int incl = part;
#pragma unroll
        for (int off = 1; off < 64; off <<= 1) {
            int v = __shfl_up(incl, off);
            if (lane >= off) incl += v;
        }
        int pre = incl - part;
        if (pre < NC && NC <= incl) {
            int cum = pre;
            for (int j = 3; j >= 0; --j) {     // walk bins high -> low
                if (cum + bc[j] >= NC) { sB1 = b0 + j; sA = cum; break; }
                cum += bc[j];
            }
        }
    }
    __syncthreads();
    const int B1 = sB1, t2 = NC - sA;      // t2 >= 1
    __syncthreads();                       // all threads captured B1 before reset
    if (tid < 256) { hist[0][tid] = 0; hist[1][tid] = 0; hist[2][tid] = 0; hist[3][tid] = 0; }
    __syncthreads();
    // pass 2: 8-bit sub-histogram within bin B1 (keys re-scanned from LDS)
#pragma unroll
    for (int i = 0; i < 48; ++i) {
        unsigned kk = keys[tid + i * 512];
        if ((int)(kk >> 8) == B1) atomicAdd(&hist[hrep][kk & 0xFF], 1u);
    }
    __syncthreads();
    // wave 0: descending scan for rank t2 within the sub-bins
    if (wave == 0) {
        const int b0 = 252 - 4 * lane;
        int bc[4];
#pragma unroll
        for (int j = 0; j < 4; ++j)
            bc[j] = (int)(hist[0][b0 + j] + hist[1][b0 + j] + hist[2][b0 + j] + hist[3][b0 + j]);
        int part = bc[0] + bc[1] + bc[2] + bc[3];
        int incl = part;
#pragma unroll
        for (int off = 1; off < 64; off <<= 1) {
            int v = __shfl_up(incl, off);
            if (lane >= off) incl += v;
        }
        int pre = incl - part;
        if (pre < t2 && t2 <= incl) {
            int cum = pre;
            for (int j = 3; j >= 0; --j) {
                if (cum + bc[j] >= t2) { sT = (B1 << 8) | (b0 + j); break; }
                cum += bc[j];
            }
        }
    }
    __syncthreads();
    const unsigned T = (unsigned)sT;
    // pass 3: compact indices with key >= T
#pragma unroll
    for (int i = 0; i < 48; ++i) {
        int idx = tid + i * 512;
        if ((unsigned)keys[idx] >= T) {
            int p = atomicAdd(&scnt, 1);
            if (p < CAP) candi[(size_t)row * CAP + p] = idx;
        }
    }
    __syncthreads();
    if (tid == 0) candn[row] = min(scnt, CAP);
}

// ----------------- epsilon-band rescue: fully wave-parallel ranking
__global__ __launch_bounds__(256) void resolve16_kernel(
    const __half* __restrict__ z, const float* __restrict__ h,
    const float* __restrict__ w2, const float* __restrict__ b2,
    const int* __restrict__ candi, const int* __restrict__ candn,
    float* __restrict__ tkv, int* __restrict__ tki) {
    const int row = blockIdx.x, tid = threadIdx.x;
    const int lane = tid & 63, wave = tid >> 6;
    __shared__ float hs[DENSE];        // 12 KB
    __shared__ float av[64];
    __shared__ int ci[64];
    __shared__ int bnd[CAP];
    __shared__ int nb_s;
    const int cnt = candn[row];
    // all threads stage h row
    const float4* hr = reinterpret_cast<const float4*>(h + (size_t)row * DENSE);
#pragma unroll
    for (int j = 0; j < 3; ++j)
        reinterpret_cast<float4*>(hs)[tid + j * 256] = hr[tid + j * 256];
    // wave 0: load candidates into lanes, rank via all-pairs shuffles
    if (wave == 0) {
        float myv = -1e30f;
        int myi = 0x7fffffff;
        if (lane < cnt) {
            myi = candi[(size_t)row * CAP + lane];
            myv = __half2float(z[(size_t)row * HID + myi]);
        }
        int rank = 0;
#pragma unroll
        for (int o = 0; o < CAP; ++o) {
            float ov = __shfl(myv, o);
            int oi = __shfl(myi, o);
            rank += ((ov > myv) || (ov == myv && oi < myi)) ? 1 : 0;
        }
        // v16 = value of the unique lane with rank 15 (cnt >= NC > 16)
        unsigned long long m15 = __ballot(rank == 15);
        int sl = (int)__builtin_ctzll(m15);
        float v16 = __shfl(myv, sl);
        bool band = (lane < cnt) && (fabsf(myv - v16) <= DELTA);
        unsigned long long bm = __ballot(band);
        if (lane == 0) nb_s = (int)__popcll(bm);
        if (band) {
            int p = (int)__popcll(bm & ((1ull << lane) - 1ull));
            bnd[p] = lane;
        }
        av[lane] = myv;
        ci[lane] = myi;
    }
    __syncthreads();
    // exact fp32 dots for band members (one wave each; nb typically ~2)
    const int nbn = nb_s;
    for (int b = wave; b < nbn; b += 4) {
        int c = bnd[b];
        int n = ci[c];
        const float4* wr = reinterpret_cast<const float4*>(w2 + (size_t)n * DENSE);
        float p = 0.0f;
#pragma unroll
        for (int j = 0; j < 12; ++j) {
            float4 a = reinterpret_cast<const float4*>(hs)[lane + j * 64];
            float4 w = wr[lane + j * 64];
            p += a.x * w.x + a.y * w.y + a.z * w.z + a.w * w.w;
        }
#pragma unroll
        for (int off = 32; off >= 1; off >>= 1) p += __shfl_down(p, off);
        if (lane == 0) av[c] = p + b2[n];   // replace approx with exact
    }
    __syncthreads();
    // wave 0: final rank over mixed values, scatter rank<16 directly
    if (wave == 0) {
        float v = av[lane];
        int idx = ci[lane];
        int rank = 0;
#pragma unroll
        for (int o = 0; o < CAP; ++o) {
            float ov = __shfl(v, o);
            int oi = __shfl(idx, o);
            rank += ((ov > v) || (ov == v && oi < idx)) ? 1 : 0;
        }
        if (lane < cnt && rank < KSEL) {
            tkv[row * KSEL + rank] = fmaxf(v, 0.0f);   // act_fn = ReLU
            tki[row * KSEL + rank] = idx;
        }
    }
}

// ------------------------------------------------------------ sparse decode
// block row: d[row,:] = gelu( sum_k val_k * w1t[idx_k, :] + b1 )
// v2: 8B gathers (uint2 = 4 halves), 16B stores.
__global__ __launch_bounds__(256) void sparse_decode_kernel(
    const float* __restrict__ tkv, const int* __restrict__ tki,
    const __half* __restrict__ w1t, const float* __restrict__ b1,
    float* __restrict__ D) {
    const int row = blockIdx.x, tid = threadIdx.x;
    __shared__ float sv[KSEL];
    __shared__ int si[KSEL];
    if (tid < KSEL) { sv[tid] = tkv[row * KSEL + tid]; si[tid] = tki[row * KSEL + tid]; }
    __syncthreads();
    float acc[3][4] = {};
#pragma unroll 1
    for (int k = 0; k < KSEL; ++k) {
        const float v = sv[k];
        const uint2* wr = reinterpret_cast<const uint2*>(w1t + (size_t)si[k] * DENSE);
#pragma unroll
        for (int j = 0; j < 3; ++j) {
            uint2 u = wr[tid + j * 256];
            float2 f0 = __half22float2(*reinterpret_cast<const __half2*>(&u.x));
            float2 f1 = __half22float2(*reinterpret_cast<const __half2*>(&u.y));
            acc[j][0] = fmaf(v, f0.x, acc[j][0]);
            acc[j][1] = fmaf(v, f0.y, acc[j][1]);
            acc[j][2] = fmaf(v, f1.x, acc[j][2]);
            acc[j][3] = fmaf(v, f1.y, acc[j][3]);
        }
    }
#pragma unroll
    for (int j = 0; j < 3; ++j) {
        int dd = (tid + j * 256) * 4;
        float4 o;
        o.x = gelu_exact(acc[j][0] + b1[dd]);
        o.y = gelu_exact(acc[j][1] + b1[dd + 1]);
        o.z = gelu_exact(acc[j][2] + b1[dd + 2]);
        o.w = gelu_exact(acc[j][3] + b1[dd + 3]);
        *reinterpret_cast<float4*>(D + (size_t)row * DENSE + dd) = o;
    }
}

// ---------------------------------------------------------------- launch
extern "C" void kernel_launch(void* const* d_in, const int* in_sizes, int n_in,
                              void* d_out, int out_size, void* d_ws, size_t ws_size,
                              hipStream_t stream) {
    const float* x      = (const float*)d_in[0];
    const float* enc_w1 = (const float*)d_in[1];
    const float* enc_b1 = (const float*)d_in[2];
    const float* enc_w2 = (const float*)d_in[3];
    const float* enc_b2 = (const float*)d_in[4];
    const float* dec_w1 = (const float*)d_in[5];
    const float* dec_b1 = (const float*)d_in[6];
    const float* dec_w2 = (const float*)d_in[7];
    const float* dec_b2 = (const float*)d_in[8];
    float* out = (float*)d_out;

    char* ws = (char*)d_ws;
    size_t off = 0;
    // region1: Wpk (enc2 W hi-only) -> later w1t (both 151.0 MB; Wpk dead after enc2)
    f16*    Wpk = (f16*)(ws + off);
    __half* w1t = (__half*)(ws + off); off += (size_t)HID * DENSE * 2;     // 151.0 MB
    __half* z    = (__half*)(ws + off); off += (size_t)MROWS * HID * 2;    //  75.5 MB
    f16*    ApkHi = (f16*)(ws + off);  off += (size_t)MROWS * DENSE * 2;   //   9.4 MB
    f16*    Dpk  = (f16*)(ws + off);   off += (size_t)MROWS * DENSE * 4;   //  18.9 MB
    float*  h    = (float*)(ws + off); off += (size_t)MROWS * DENSE * 4;   //  18.9 MB
    float*  dbuf = (float*)(ws + off); off += (size_t)MROWS * DENSE * 4;   //  18.9 MB
    f16*    W1pk = (f16*)(ws + off);
    f16*    Wd2pk = (f16*)(ws + off);  off += (size_t)DENSE * DIM * 4;     //   9.4 MB
    f16*    xcpk = (f16*)(ws + off);   off += (size_t)MROWS * DIM * 4;     //   4.7 MB
    float*  tkv  = (float*)(ws + off); off += (size_t)MROWS * KSEL * 4;
    int*    tki  = (int*)(ws + off);   off += (size_t)MROWS * KSEL * 4;
    int*    candi = (int*)(ws + off);  off += (size_t)MROWS * CAP * 4;
    int*    candn = (int*)(ws + off);  off += (size_t)MROWS * 4;

    // xcpk = split(x - dec_b2); W1pk = split(enc_w1)   (merged)
    prep1_kernel<<<576 + 1152, 256, 0, stream>>>(x, dec_b2, xcpk, enc_w1, W1pk);
    // h = gelu(xc @ enc_w1^T + b1)   (3-term, fp32-equivalent)
    mfma_nt_kernel<24, 1><<<dim3(12, 24), 256, 0, stream>>>(
        xcpk, W1pk, enc_b1, h, DENSE, 0);
    // ApkHi = fp16(h); Wpk = fp16(enc_w2)   (merged)
    prep2_kernel<<<2304 + 36864, 256, 0, stream>>>(h, ApkHi, enc_w2, Wpk);
    // z ~= h @ enc_w2^T + b2  (fp16 out; 3-buf 1-barrier pipeline, FROZEN v3)
    enc2v3_kernel<<<dim3(6, 192), 512, 0, stream>>>(ApkHi, Wpk, enc_b2, z);
    // w1t = transpose(decoder_w1) fp16 (overwrites Wpk — dead after enc2)
    transpose_w1_kernel<<<dim3(HID / 32, DENSE / 32), 256, 0, stream>>>(dec_w1, w1t);
    // radix-select candidate superset (>= NC) per row — replicated histograms
    topksel_kernel<<<MROWS, 512, 0, stream>>>(z, candi, candn);
    // epsilon-band exact rescue (wave-parallel ranks) -> exact top-16 set
    resolve16_kernel<<<MROWS, 256, 0, stream>>>(
        z, h, enc_w2, enc_b2, candi, candn, tkv, tki);
    // d = gelu(sparse decode + b1) — 8B gathers of w1t rows (L3-resident)
    sparse_decode_kernel<<<MROWS, 256, 0, stream>>>(tkv, tki, w1t, dec_b1, dbuf);
    // Dpk = split(d)
    apack_kernel<96, 96><<<96 * 96 / 4, 256, 0, stream>>>(dbuf, Dpk);
    // Wd2pk = split(dec_w2)
    wpack_kernel<96><<<6 * 96 * 8 / 4, 256, 0, stream>>>(dec_w2, Wd2pk, 0);
    // out = d @ dec_w2^T + dec_b2   (3-term, 64x64 tiles for occupancy)
    mfma64_kernel<<<dim3(24, 12), 256, 0, stream>>>(Dpk, Wd2pk, dec_b2, out);
}

// Round 18
// 541.680 us; speedup vs baseline: 1.2228x; 1.0851x over previous
//
#include <hip/hip_runtime.h>
#include <hip/hip_fp16.h>

#define DIM 768
#define HID 24576
#define DENSE 3072
#define LL 24
#define MROWS 1536
#define KSEL 16
#define NC 24              // certified candidate rank (true top-16 in approx top-24)
#define CAP 40             // candidate capacity (NC + threshold ties)
#define MF_TOT 96          // MROWS/16
#define ENC2_NT 96         // DENSE/32 K-tiles for enc2 (BK=32)
#define DELTA 2e-3f        // band half-width >= 2x max |fp16-z - true z| (~5e-4)

typedef _Float16 f16;
typedef __attribute__((ext_vector_type(8))) _Float16 f16x8;
typedef __attribute__((ext_vector_type(4))) float f32x4;
typedef const __attribute__((address_space(1))) char* gcp;
typedef __attribute__((address_space(3))) char* lcp;

__device__ __forceinline__ float gelu_exact(float x) {
    return 0.5f * x * (1.0f + erff(x * 0.7071067811865476f));
}

// ---------------------------------------------------------- fp16 hi/lo split
__device__ __forceinline__ void split8(const float4& v0, const float4& v1,
                                       f16x8& hi, f16x8& lo) {
    float vv[8] = {v0.x, v0.y, v0.z, v0.w, v1.x, v1.y, v1.z, v1.w};
#pragma unroll
    for (int j = 0; j < 8; ++j) {
        f16 h = (f16)vv[j];
        hi[j] = h;
        lo[j] = (f16)((vv[j] - (float)h) * 2048.0f);
    }
}

// Fragment packing: chunk = 64 lanes x 16B; lane holds 8 halves for
// (row = base + (lane&15), k = ks*32 + (lane>>4)*8 + j). Same packing for A
// and W => K-slot permutation cancels inside MFMA.

// prep1: blocks [0,576) = xcpack (x - dec_b2, hi/lo); [576,1728) = wpack24(enc_w1)
__global__ __launch_bounds__(256) void prep1_kernel(
    const float* __restrict__ x, const float* __restrict__ b2,
    f16* __restrict__ xcpk,
    const float* __restrict__ w1src, f16* __restrict__ W1pk) {
    int lane = threadIdx.x & 63;
    if (blockIdx.x < 576) {
        int c = blockIdx.x * 4 + (threadIdx.x >> 6);
        int rf = c % MF_TOT, ks = c / MF_TOT;
        int m = rf * 16 + (lane & 15);
        int k = ks * 32 + (lane >> 4) * 8;
        const float4* sx = (const float4*)(x + (size_t)m * DIM + k);
        const float4* sb = (const float4*)(b2 + (m % LL) * DIM + k);
        float4 v0 = sx[0], v1 = sx[1], b0 = sb[0], b1 = sb[1];
        v0.x -= b0.x; v0.y -= b0.y; v0.z -= b0.z; v0.w -= b0.w;
        v1.x -= b1.x; v1.y -= b1.y; v1.z -= b1.z; v1.w -= b1.w;
        f16x8 hi, lo;
        split8(v0, v1, hi, lo);
        char* base = (char*)xcpk + (size_t)c * 2048 + lane * 16;
        *(f16x8*)base = hi;
        *(f16x8*)(base + 1024) = lo;
    } else {
        int c = (blockIdx.x - 576) * 4 + (threadIdx.x >> 6);
        int nf = c & 7; int t = c >> 3; int ks = t % 24; int nb = t / 24;
        int n = nb * 128 + nf * 16 + (lane & 15);
        int k = ks * 32 + (lane >> 4) * 8;
        const float4* s = (const float4*)(w1src + (size_t)n * DIM + k);
        f16x8 hi, lo;
        split8(s[0], s[1], hi, lo);
        char* base = (char*)W1pk + (size_t)c * 2048 + lane * 16;
        *(f16x8*)base = hi;
        *(f16x8*)(base + 1024) = lo;
    }
}

// prep2: [0,2304) apackhi(h); [2304,39168) wpackhi(enc_w2); [39168,40320) wpack96(dec_w2)
__global__ __launch_bounds__(256) void prep2_kernel(
    const float* __restrict__ h, f16* __restrict__ ApkHi,
    const float* __restrict__ w2, f16* __restrict__ Wpk,
    const float* __restrict__ wd2, f16* __restrict__ Wd2pk) {
    int lane = threadIdx.x & 63;
    if (blockIdx.x < 2304) {
        int c = blockIdx.x * 4 + (threadIdx.x >> 6);
        int rf = c % MF_TOT, ks = c / MF_TOT;
        int m = rf * 16 + (lane & 15);
        int k = ks * 32 + (lane >> 4) * 8;
        const float4* s = (const float4*)(h + (size_t)m * DENSE + k);
        float4 v0 = s[0], v1 = s[1];
        float vv[8] = {v0.x, v0.y, v0.z, v0.w, v1.x, v1.y, v1.z, v1.w};
        f16x8 hi;
#pragma unroll
        for (int j = 0; j < 8; ++j) hi[j] = (f16)vv[j];
        *(f16x8*)((char*)ApkHi + (size_t)c * 1024 + lane * 16) = hi;
    } else if (blockIdx.x < 39168) {
        int c = (blockIdx.x - 2304) * 4 + (threadIdx.x >> 6);
        int nf = c & 7; int t = c >> 3; int ks = t % 96; int nb = t / 96;
        int n = nb * 128 + nf * 16 + (lane & 15);
        int k = ks * 32 + (lane >> 4) * 8;
        const float4* s = (const float4*)(w2 + (size_t)n * DENSE + k);
        float4 v0 = s[0], v1 = s[1];
        float vv[8] = {v0.x, v0.y, v0.z, v0.w, v1.x, v1.y, v1.z, v1.w};
        f16x8 hi;
#pragma unroll
        for (int j = 0; j < 8; ++j) hi[j] = (f16)vv[j];
        *(f16x8*)((char*)Wpk + (size_t)c * 1024 + lane * 16) = hi;
    } else {
        int c = (blockIdx.x - 39168) * 4 + (threadIdx.x >> 6);
        int nf = c & 7; int t = c >> 3; int ks = t % 96; int nb = t / 96;
        int n = nb * 128 + nf * 16 + (lane & 15);
        int k = ks * 32 + (lane >> 4) * 8;
        const float4* s = (const float4*)(wd2 + (size_t)n * DENSE + k);
        f16x8 hi, lo;
        split8(s[0], s[1], hi, lo);
        char* base = (char*)Wd2pk + (size_t)c * 2048 + lane * 16;
        *(f16x8*)base = hi;
        *(f16x8*)(base + 1024) = lo;
    }
}

// ------------------------------------------------- split-fp16 MFMA GEMM (NT)
// 3-term fp32-equivalent (enc1 EPI=1) — proven m97-style structure
template <int KTOT, int EPI>
__global__ __launch_bounds__(256, 2) void mfma_nt_kernel(
    const f16* __restrict__ Apk, const f16* __restrict__ Wpk,
    const float* __restrict__ bias, float* __restrict__ C,
    int N, int n0g) {
    __shared__ __align__(16) char lds[2][32768];
    const int tid = threadIdx.x;
    const int lane = tid & 63, wave = tid >> 6;
    const int mb = blockIdx.x, nb = blockIdx.y;
    const int wr = wave >> 1, wc = wave & 1;
    const char* ApkB = (const char*)Apk;
    const char* WpkB = (const char*)Wpk;

    f32x4 accH[4][4] = {}; f32x4 accL[4][4] = {};

    auto stage = [&](int buf, int ks) {
        const char* Ar = ApkB + (size_t)(ks * MF_TOT + mb * 8) * 2048;
        const char* Wr = WpkB + (size_t)(nb * KTOT + ks) * 16384;
#pragma unroll
        for (int q = 0; q < 8; ++q) {
            int c = wave * 8 + q;
            const char* src = (c < 16 ? Ar + c * 1024 : Wr + (c - 16) * 1024) + lane * 16;
            char* dst = &lds[buf][c * 1024];
            __builtin_amdgcn_global_load_lds((gcp)src, (lcp)dst, 16, 0, 0);
        }
    };

    stage(0, 0);
    for (int ks = 0; ks < KTOT; ++ks) {
        int cur = ks & 1;
        __syncthreads();
        if (ks + 1 < KTOT) stage(cur ^ 1, ks + 1);
        const char* Bf = lds[cur];
        f16x8 Ahi[4], Alo[4], Whi[4], Wlo[4];
#pragma unroll
        for (int i = 0; i < 4; ++i) {
            Ahi[i] = *(const f16x8*)(Bf + ((wr * 4 + i) * 2 + 0) * 1024 + lane * 16);
            Alo[i] = *(const f16x8*)(Bf + ((wr * 4 + i) * 2 + 1) * 1024 + lane * 16);
            Whi[i] = *(const f16x8*)(Bf + 16384 + ((wc * 4 + i) * 2 + 0) * 1024 + lane * 16);
            Wlo[i] = *(const f16x8*)(Bf + 16384 + ((wc * 4 + i) * 2 + 1) * 1024 + lane * 16);
        }
#pragma unroll
        for (int i = 0; i < 4; ++i)
#pragma unroll
            for (int j = 0; j < 4; ++j) {
                accH[i][j] = __builtin_amdgcn_mfma_f32_16x16x32_f16(Ahi[i], Whi[j], accH[i][j], 0, 0, 0);
                accL[i][j] = __builtin_amdgcn_mfma_f32_16x16x32_f16(Ahi[i], Wlo[j], accL[i][j], 0, 0, 0);
                accL[i][j] = __builtin_amdgcn_mfma_f32_16x16x32_f16(Alo[i], Whi[j], accL[i][j], 0, 0, 0);
            }
    }
    const int rbase = mb * 128 + wr * 64 + (lane >> 4) * 4;
    const int cb = n0g + nb * 128 + wc * 64 + (lane & 15);
#pragma unroll
    for (int j = 0; j < 4; ++j) {
        int col = cb + j * 16;
        float bn = (EPI == 2) ? 0.0f : bias[col];
#pragma unroll
        for (int i = 0; i < 4; ++i) {
#pragma unroll
            for (int e = 0; e < 4; ++e) {
                int row = rbase + i * 16 + e;
                float v = accH[i][j][e] + accL[i][j][e] * (1.0f / 2048.0f);
                if (EPI == 1)       v = gelu_exact(v + bn);
                else if (EPI == 0)  v += bn;
                else                v += bias[(row % LL) * N + col];
                C[(size_t)row * N + col] = v;
            }
        }
    }
}

// --------- mfma64: 64x64-tile 3-term GEMM for dec2 (EPI=2), 288 blocks
__global__ __launch_bounds__(256, 4) void mfma64_kernel(
    const f16* __restrict__ Apk, const f16* __restrict__ Wpk,
    const float* __restrict__ bias, float* __restrict__ C) {
    __shared__ __align__(16) char lds[2][16384];   // A 8KB | W 8KB
    const int tid = threadIdx.x;
    const int lane = tid & 63, wave = tid >> 6;
    const int mb = blockIdx.x, nbi = blockIdx.y;   // 24 x 12
    const int wr = wave >> 1, wc = wave & 1;
    const char* ApkB = (const char*)Apk;
    const char* WpkB = (const char*)Wpk;

    f32x4 accH[2][2] = {}; f32x4 accL[2][2] = {};

    auto stage = [&](int buf, int ks) {
        const char* Ar = ApkB + (size_t)(ks * 96 + mb * 4) * 2048;
        const char* Wr = WpkB + (((size_t)(nbi >> 1) * 96 + ks) * 8 + (nbi & 1) * 4) * 2048;
#pragma unroll
        for (int q = 0; q < 2; ++q) {
            __builtin_amdgcn_global_load_lds(
                (gcp)(Ar + tid * 16 + q * 4096),
                (lcp)(&lds[buf][0] + (tid & ~63) * 16 + q * 4096), 16, 0, 0);
            __builtin_amdgcn_global_load_lds(
                (gcp)(Wr + tid * 16 + q * 4096),
                (lcp)(&lds[buf][8192] + (tid & ~63) * 16 + q * 4096), 16, 0, 0);
        }
    };

    stage(0, 0);
    for (int ks = 0; ks < 96; ++ks) {
        int cur = ks & 1;
        __syncthreads();
        if (ks + 1 < 96) stage(cur ^ 1, ks + 1);
        const char* Bf = lds[cur];
        f16x8 Ahi[2], Alo[2], Whi[2], Wlo[2];
#pragma unroll
        for (int i = 0; i < 2; ++i) {
            Ahi[i] = *(const f16x8*)(Bf + (wr * 2 + i) * 2048 + lane * 16);
            Alo[i] = *(const f16x8*)(Bf + (wr * 2 + i) * 2048 + 1024 + lane * 16);
            Whi[i] = *(const f16x8*)(Bf + 8192 + (wc * 2 + i) * 2048 + lane * 16);
            Wlo[i] = *(const f16x8*)(Bf + 8192 + (wc * 2 + i) * 2048 + 1024 + lane * 16);
        }
#pragma unroll
        for (int i = 0; i < 2; ++i)
#pragma unroll
            for (int j = 0; j < 2; ++j) {
                accH[i][j] = __builtin_amdgcn_mfma_f32_16x16x32_f16(Ahi[i], Whi[j], accH[i][j], 0, 0, 0);
                accL[i][j] = __builtin_amdgcn_mfma_f32_16x16x32_f16(Ahi[i], Wlo[j], accL[i][j], 0, 0, 0);
                accL[i][j] = __builtin_amdgcn_mfma_f32_16x16x32_f16(Alo[i], Whi[j], accL[i][j], 0, 0, 0);
            }
    }
    const int rbase = mb * 64 + wr * 32 + (lane >> 4) * 4;
    const int cb = nbi * 64 + wc * 32 + (lane & 15);
#pragma unroll
    for (int j = 0; j < 2; ++j) {
        int col = cb + j * 16;
#pragma unroll
        for (int i = 0; i < 2; ++i) {
#pragma unroll
            for (int e = 0; e < 4; ++e) {
                int row = rbase + i * 16 + e;
                float v = accH[i][j][e] + accL[i][j][e] * (1.0f / 2048.0f)
                        + bias[(row % LL) * DIM + col];
                C[(size_t)row * DIM + col] = v;
            }
        }
    }
}

// ---------------- enc2 v3 (FROZEN): 3-buffer / 1-barrier 256x128 fp16 MFMA
__global__ __launch_bounds__(512, 4) void enc2v3_kernel(
    const f16* __restrict__ Apk, const f16* __restrict__ Wpk,
    const float* __restrict__ b2, __half* __restrict__ z) {
    __shared__ __align__(16) char lds[3][24576];   // per buf: A 16KB | W 8KB
    const int tid = threadIdx.x;
    const int lane = tid & 63, wave = tid >> 6;
    // bijective XCD-chunked swizzle: 1152 blocks = 8 x 144
    int f = blockIdx.y * 6 + blockIdx.x;
    int ff = (f & 7) * 144 + (f >> 3);
    const int mb = ff % 6, nb = ff / 6;            // BM=256 (6), BN=128 (192)
    const int wr = wave >> 1, wc = wave & 1;       // 4M x 2N wave grid
    const char* ApkB = (const char*)Apk;
    const char* WpkB = (const char*)Wpk;
    f32x4 acc[4][4] = {};

    auto stage = [&](int t) {                      // tile t -> buf t%3 (3 loads)
        if (t >= ENC2_NT) return;
        char* dst = lds[t % 3];
        const char* Asrc = ApkB + ((size_t)t * MF_TOT + mb * 16) * 1024;
        __builtin_amdgcn_global_load_lds((gcp)(Asrc + tid * 16),
                                         (lcp)(dst + (tid & ~63) * 16), 16, 0, 0);
        __builtin_amdgcn_global_load_lds((gcp)(Asrc + tid * 16 + 8192),
                                         (lcp)(dst + (tid & ~63) * 16 + 8192), 16, 0, 0);
        const char* Wsrc = WpkB + ((size_t)nb * 96 + t) * 8192;
        __builtin_amdgcn_global_load_lds((gcp)(Wsrc + tid * 16),
                                         (lcp)(dst + 16384 + (tid & ~63) * 16), 16, 0, 0);
    };

    stage(0); stage(1);
    asm volatile("s_waitcnt vmcnt(3)" ::: "memory");   // tile0 landed, tile1 in flight
    __builtin_amdgcn_s_barrier();

    for (int t = 0; t < ENC2_NT; ++t) {
        const char* Bf = lds[t % 3];
        f16x8 Af[4], Wf[4];
#pragma unroll
        for (int i = 0; i < 4; ++i) {
            Af[i] = *(const f16x8*)(Bf + (wr * 4 + i) * 1024 + lane * 16);
            Wf[i] = *(const f16x8*)(Bf + 16384 + (wc * 4 + i) * 1024 + lane * 16);
        }
        stage(t + 2);          // targets buf[(t+2)%3]: not read this phase or next
        __builtin_amdgcn_s_setprio(1);
#pragma unroll
        for (int i = 0; i < 4; ++i)
#pragma unroll
            for (int j = 0; j < 4; ++j)
                acc[i][j] = __builtin_amdgcn_mfma_f32_16x16x32_f16(Af[i], Wf[j], acc[i][j], 0, 0, 0);
        __builtin_amdgcn_s_setprio(0);
        // boundary: t+1's loads (issued phase t-1) must land; t+2's 3 may fly
        if (t < ENC2_NT - 2)      asm volatile("s_waitcnt vmcnt(3)" ::: "memory");
        else if (t < ENC2_NT - 1) asm volatile("s_waitcnt vmcnt(0)" ::: "memory");
        if (t < ENC2_NT - 1) __builtin_amdgcn_s_barrier();
    }
    // epilogue: fp16 z
    const int rbase = mb * 256 + wr * 64 + (lane >> 4) * 4;
    const int cb = nb * 128 + wc * 64 + (lane & 15);
#pragma unroll
    for (int j = 0; j < 4; ++j) {
        int col = cb + j * 16;
        float bn = b2[col];
#pragma unroll
        for (int r = 0; r < 4; ++r)
#pragma unroll
            for (int e = 0; e < 4; ++e)
                z[(size_t)(rbase + r * 16 + e) * HID + col] = __float2half(acc[r][j][e] + bn);
    }
}

// ------------------- radix-select v3: two-level 256-bin, x4 replicated hist
__global__ __launch_bounds__(512) void topksel_kernel(
    const __half* __restrict__ z, int* __restrict__ candi, int* __restrict__ candn) {
    __shared__ unsigned short keys[HID];   // 48 KB
    __shared__ unsigned hist[4][256];      // 4 KB (x4 replicated: less contention)
    __shared__ int sB1, sA, sT, scnt;
    const int row = blockIdx.x, tid = threadIdx.x;
    const int lane = tid & 63, wave = tid >> 6;
    const int hrep = wave & 3;
    const uint4* zr = reinterpret_cast<const uint4*>(z + (size_t)row * HID);
    if (tid < 256) { hist[0][tid] = 0; hist[1][tid] = 0; hist[2][tid] = 0; hist[3][tid] = 0; }
    if (tid == 0) scnt = 0;
    __syncthreads();
    // pass 1: stage keys + 8-bit histogram (key[15:8])
#pragma unroll
    for (int i = 0; i < 6; ++i) {
        uint4 v = zr[tid + i * 512];
        unsigned w[4] = {v.x, v.y, v.z, v.w};
        int base = (tid + i * 512) * 8;
#pragma unroll
        for (int q = 0; q < 4; ++q)
#pragma unroll
            for (int s = 0; s < 2; ++s) {
                unsigned b = (w[q] >> (16 * s)) & 0xFFFFu;
                unsigned kk = b ^ ((b & 0x8000u) ? 0xFFFFu : 0x8000u);
                keys[base + q * 2 + s] = (unsigned short)kk;
                atomicAdd(&hist[hrep][kk >> 8], 1u);
            }
    }
    __syncthreads();
    // wave 0: descending cumulative scan, find bin of rank NC
    if (wave == 0) {
        const int b0 = 252 - 4 * lane;     // lane 0 owns top bins 252..255
        int bc[4];
#pragma unroll
        for (int j = 0; j < 4; ++j)
            bc[j] = (int)(hist[0][b0 + j] + hist[1][b0 + j] + hist[2][b0 + j] + hist[3][b0 + j]);
        int part = bc[0] + bc[1] + bc[2] + bc[3];
        int incl = part;
#pragma unroll
        for (int off = 1; off < 64; off <<= 1) {
            int v = __shfl_up(incl, off);
            if (lane >= off) incl += v;
        }
        int pre = incl - part;
        if (pre < NC && NC <= incl) {
            int cum = pre;
            for (int j = 3; j >= 0; --j) {     // walk bins high -> low
                if (cum + bc[j] >= NC) { sB1 = b0 + j; sA = cum; break; }
                cum += bc[j];
            }
        }
    }
    __syncthreads();
    const int B1 = sB1, t2 = NC - sA;      // t2 >= 1
    __syncthreads();                       // all threads captured B1 before reset
    if (tid < 256) { hist[0][tid] = 0; hist[1][tid] = 0; hist[2][tid] = 0; hist[3][tid] = 0; }
    __syncthreads();
    // pass 2: 8-bit sub-histogram within bin B1 (keys re-scanned from LDS)
#pragma unroll
    for (int i = 0; i < 48; ++i) {
        unsigned kk = keys[tid + i * 512];
        if ((int)(kk >> 8) == B1) atomicAdd(&hist[hrep][kk & 0xFF], 1u);
    }
    __syncthreads();
    // wave 0: descending scan for rank t2 within the sub-bins
    if (wave == 0) {
        const int b0 = 252 - 4 * lane;
        int bc[4];
#pragma unroll
        for (int j = 0; j < 4; ++j)
            bc[j] = (int)(hist[0][b0 + j] + hist[1][b0 + j] + hist[2][b0 + j] + hist[3][b0 + j]);
        int part = bc[0] + bc[1] + bc[2] + bc[3];
        int incl = part;
#pragma unroll
        for (int off = 1; off < 64; off <<= 1) {
            int v = __shfl_up(incl, off);
            if (lane >= off) incl += v;
        }
        int pre = incl - part;
        if (pre < t2 && t2 <= incl) {
            int cum = pre;
            for (int j = 3; j >= 0; --j) {
                if (cum + bc[j] >= t2) { sT = (B1 << 8) | (b0 + j); break; }
                cum += bc[j];
            }
        }
    }
    __syncthreads();
    const unsigned T = (unsigned)sT;
    // pass 3: compact indices with key >= T
#pragma unroll
    for (int i = 0; i < 48; ++i) {
        int idx = tid + i * 512;
        if ((unsigned)keys[idx] >= T) {
            int p = atomicAdd(&scnt, 1);
            if (p < CAP) candi[(size_t)row * CAP + p] = idx;
        }
    }
    __syncthreads();
    if (tid == 0) candn[row] = min(scnt, CAP);
}

// ----------------- epsilon-band rescue: fully wave-parallel ranking
__global__ __launch_bounds__(256) void resolve16_kernel(
    const __half* __restrict__ z, const float* __restrict__ h,
    const float* __restrict__ w2, const float* __restrict__ b2,
    const int* __restrict__ candi, const int* __restrict__ candn,
    float* __restrict__ tkv, int* __restrict__ tki) {
    const int row = blockIdx.x, tid = threadIdx.x;
    const int lane = tid & 63, wave = tid >> 6;
    __shared__ float hs[DENSE];        // 12 KB
    __shared__ float av[64];
    __shared__ int ci[64];
    __shared__ int bnd[CAP];
    __shared__ int nb_s;
    const int cnt = candn[row];
    // all threads stage h row
    const float4* hr = reinterpret_cast<const float4*>(h + (size_t)row * DENSE);
#pragma unroll
    for (int j = 0; j < 3; ++j)
        reinterpret_cast<float4*>(hs)[tid + j * 256] = hr[tid + j * 256];
    // wave 0: load candidates into lanes, rank via all-pairs shuffles
    if (wave == 0) {
        float myv = -1e30f;
        int myi = 0x7fffffff;
        if (lane < cnt) {
            myi = candi[(size_t)row * CAP + lane];
            myv = __half2float(z[(size_t)row * HID + myi]);
        }
        int rank = 0;
#pragma unroll
        for (int o = 0; o < CAP; ++o) {
            float ov = __shfl(myv, o);
            int oi = __shfl(myi, o);
            rank += ((ov > myv) || (ov == myv && oi < myi)) ? 1 : 0;
        }
        // v16 = value of the unique lane with rank 15 (cnt >= NC > 16)
        unsigned long long m15 = __ballot(rank == 15);
        int sl = (int)__builtin_ctzll(m15);
        float v16 = __shfl(myv, sl);
        bool band = (lane < cnt) && (fabsf(myv - v16) <= DELTA);
        unsigned long long bm = __ballot(band);
        if (lane == 0) nb_s = (int)__popcll(bm);
        if (band) {
            int p = (int)__popcll(bm & ((1ull << lane) - 1ull));
            bnd[p] = lane;
        }
        av[lane] = myv;
        ci[lane] = myi;
    }
    __syncthreads();
    // exact fp32 dots for band members (one wave each; nb typically ~2)
    const int nbn = nb_s;
    for (int b = wave; b < nbn; b += 4) {
        int c = bnd[b];
        int n = ci[c];
        const float4* wr = reinterpret_cast<const float4*>(w2 + (size_t)n * DENSE);
        float p = 0.0f;
#pragma unroll
        for (int j = 0; j < 12; ++j) {
            float4 a = reinterpret_cast<const float4*>(hs)[lane + j * 64];
            float4 w = wr[lane + j * 64];
            p += a.x * w.x + a.y * w.y + a.z * w.z + a.w * w.w;
        }
#pragma unroll
        for (int off = 32; off >= 1; off >>= 1) p += __shfl_down(p, off);
        if (lane == 0) av[c] = p + b2[n];   // replace approx with exact
    }
    __syncthreads();
    // wave 0: final rank over mixed values, scatter rank<16 directly
    if (wave == 0) {
        float v = av[lane];
        int idx = ci[lane];
        int rank = 0;
#pragma unroll
        for (int o = 0; o < CAP; ++o) {
            float ov = __shfl(v, o);
            int oi = __shfl(idx, o);
            rank += ((ov > v) || (ov == v && oi < idx)) ? 1 : 0;
        }
        if (lane < cnt && rank < KSEL) {
            tkv[row * KSEL + rank] = fmaxf(v, 0.0f);   // act_fn = ReLU
            tki[row * KSEL + rank] = idx;
        }
    }
}

// ------------- sparse decode, transposed, direct dec_w1 read (v2)
// block r: dT[r, row] = gelu( sum_k v_k(row) * dec_w1[r, i_k(row)] + b1[r] )
// R9 fixes: LDS = 48KB wrow ONLY (3 blocks/CU, 24 waves); (v,idx) pairs in
// registers (unrolled); no per-chunk barriers.
__global__ __launch_bounds__(512) void sparse_decodeT_kernel(
    const float* __restrict__ tkv, const int* __restrict__ tki,
    const float* __restrict__ w1, const float* __restrict__ b1,
    float* __restrict__ dT) {
    __shared__ __half wrow[HID];          // 48 KB
    const int r = blockIdx.x, tid = threadIdx.x;
    const float4* wr4 = reinterpret_cast<const float4*>(w1 + (size_t)r * HID);
#pragma unroll
    for (int i = 0; i < 12; ++i) {
        float4 v = wr4[tid + i * 512];
        int p = (tid + i * 512) * 4;
        uint2 packed;
        __half2 h01 = __floats2half2_rn(v.x, v.y);
        __half2 h23 = __floats2half2_rn(v.z, v.w);
        packed.x = *reinterpret_cast<const unsigned*>(&h01);
        packed.y = *reinterpret_cast<const unsigned*>(&h23);
        *reinterpret_cast<uint2*>(&wrow[p]) = packed;
    }
    const float b1r = b1[r];
    __syncthreads();
#pragma unroll
    for (int c = 0; c < 3; ++c) {         // 512 output rows per chunk
        const int row = c * 512 + tid;
        float sv[KSEL];
        int si[KSEL];
#pragma unroll
        for (int k = 0; k < KSEL; ++k) {
            sv[k] = tkv[row * KSEL + k];
            si[k] = tki[row * KSEL + k];
        }
        float acc = 0.0f;
#pragma unroll
        for (int k = 0; k < KSEL; ++k)
            acc = fmaf(sv[k], __half2float(wrow[si[k]]), acc);
        dT[(size_t)r * MROWS + row] = gelu_exact(acc + b1r);
    }
}

// ----------------------------- transposing pack: dT [DENSE][MROWS] -> Dpk hi/lo
__global__ __launch_bounds__(256) void dpackT_kernel(
    const float* __restrict__ dT, f16* __restrict__ dst) {
    int c = blockIdx.x * 4 + (threadIdx.x >> 6);
    int lane = threadIdx.x & 63;
    int rf = c % 96, ks = c / 96;
    int m = rf * 16 + (lane & 15);
    int k0 = ks * 32 + (lane >> 4) * 8;
    f16x8 hi, lo;
#pragma unroll
    for (int j = 0; j < 8; ++j) {
        float v = dT[(size_t)(k0 + j) * MROWS + m];
        f16 hh = (f16)v;
        hi[j] = hh;
        lo[j] = (f16)((v - (float)hh) * 2048.0f);
    }
    char* base = (char*)dst + (size_t)c * 2048 + lane * 16;
    *(f16x8*)base = hi;
    *(f16x8*)(base + 1024) = lo;
}

// ---------------------------------------------------------------- launch
extern "C" void kernel_launch(void* const* d_in, const int* in_sizes, int n_in,
                              void* d_out, int out_size, void* d_ws, size_t ws_size,
                              hipStream_t stream) {
    const float* x      = (const float*)d_in[0];
    const float* enc_w1 = (const float*)d_in[1];
    const float* enc_b1 = (const float*)d_in[2];
    const float* enc_w2 = (const float*)d_in[3];
    const float* enc_b2 = (const float*)d_in[4];
    const float* dec_w1 = (const float*)d_in[5];
    const float* dec_b1 = (const float*)d_in[6];
    const float* dec_w2 = (const float*)d_in[7];
    const float* dec_b2 = (const float*)d_in[8];
    float* out = (float*)d_out;

    char* ws = (char*)d_ws;
    size_t off = 0;
    f16*    Wpk  = (f16*)(ws + off);   off += (size_t)HID * DENSE * 2;     // 151.0 MB
    __half* z    = (__half*)(ws + off); off += (size_t)MROWS * HID * 2;    //  75.5 MB
    f16*    ApkHi = (f16*)(ws + off);  off += (size_t)MROWS * DENSE * 2;   //   9.4 MB
    f16*    Dpk  = (f16*)(ws + off);   off += (size_t)MROWS * DENSE * 4;   //  18.9 MB
    float*  h    = (float*)(ws + off); off += (size_t)MROWS * DENSE * 4;   //  18.9 MB
    float*  dT   = (float*)(ws + off); off += (size_t)DENSE * MROWS * 4;   //  18.9 MB
    f16*    W1pk = (f16*)(ws + off);
    f16*    Wd2pk = (f16*)(ws + off);  off += (size_t)DENSE * DIM * 4;     //   9.4 MB
    f16*    xcpk = (f16*)(ws + off);   off += (size_t)MROWS * DIM * 4;     //   4.7 MB
    float*  tkv  = (float*)(ws + off); off += (size_t)MROWS * KSEL * 4;
    int*    tki  = (int*)(ws + off);   off += (size_t)MROWS * KSEL * 4;
    int*    candi = (int*)(ws + off);  off += (size_t)MROWS * CAP * 4;
    int*    candn = (int*)(ws + off);  off += (size_t)MROWS * 4;

    // xcpk = split(x - dec_b2); W1pk = split(enc_w1)   (merged)
    prep1_kernel<<<576 + 1152, 256, 0, stream>>>(x, dec_b2, xcpk, enc_w1, W1pk);
    // h = gelu(xc @ enc_w1^T + b1)   (3-term, fp32-equivalent)
    mfma_nt_kernel<24, 1><<<dim3(12, 24), 256, 0, stream>>>(
        xcpk, W1pk, enc_b1, h, DENSE, 0);
    // ApkHi = fp16(h); Wpk = fp16(enc_w2); Wd2pk = split(dec_w2)  (merged;
    // Wd2pk region = W1pk region, dead after enc1)
    prep2_kernel<<<2304 + 36864 + 1152, 256, 0, stream>>>(
        h, ApkHi, enc_w2, Wpk, dec_w2, Wd2pk);
    // z ~= h @ enc_w2^T + b2  (fp16 out; 3-buf 1-barrier pipeline, FROZEN v3)
    enc2v3_kernel<<<dim3(6, 192), 512, 0, stream>>>(ApkHi, Wpk, enc_b2, z);
    // radix-select candidate superset (>= NC) per row — replicated histograms
    topksel_kernel<<<MROWS, 512, 0, stream>>>(z, candi, candn);
    // epsilon-band exact rescue (wave-parallel ranks) -> exact top-16 set
    resolve16_kernel<<<MROWS, 256, 0, stream>>>(
        z, h, enc_w2, enc_b2, candi, candn, tkv, tki);
    // dT = gelu(sparse decode + b1), transposed — direct dec_w1 read
    sparse_decodeT_kernel<<<DENSE, 512, 0, stream>>>(tkv, tki, dec_w1, dec_b1, dT);
    // Dpk = split(dT^T)  (transposing pack)
    dpackT_kernel<<<96 * 96 / 4, 256, 0, stream>>>(dT, Dpk);
    // out = d @ dec_w2^T + dec_b2   (3-term, 64x64 tiles for occupancy)
    mfma64_kernel<<<dim3(24, 12), 256, 0, stream>>>(Dpk, Wd2pk, dec_b2, out);
}